// Round 10
// baseline (630.778 us; speedup 1.0000x reference)
//
#include <hip/hip_runtime.h>
#include <hip/hip_bf16.h>
#include <cstdint>
#include <cstddef>

#define T_SEQ 4096
#define HID   2048
#define NH    16
#define HD    128
#define QKVN  6144
#define KVB   32

typedef unsigned short u16;
typedef unsigned int u32;
typedef __bf16 bf16x8 __attribute__((ext_vector_type(8)));
typedef float  f32x4  __attribute__((ext_vector_type(4)));

typedef const __attribute__((address_space(1))) void* gas_ptr;
typedef __attribute__((address_space(3))) void* las_ptr;

__device__ __forceinline__ void async16(const void* g, void* l) {
  __builtin_amdgcn_global_load_lds((gas_ptr)g, (las_ptr)l, 16, 0, 0);
}

__device__ __forceinline__ u16 f2bf(float f) {
  unsigned int u = __float_as_uint(f);
  u += 0x7fffu + ((u >> 16) & 1u);
  return (u16)(u >> 16);
}

__device__ __forceinline__ float bf2f(u16 x) {
  return __uint_as_float((unsigned)x << 16);
}

// ---------------- elementwise cast f32 -> bf16 ----------------
__global__ void cast_f32_bf16(const float* __restrict__ in, u16* __restrict__ out, int n) {
  int i = (blockIdx.x * blockDim.x + threadIdx.x) * 4;
  if (i >= n) return;
  float4 v = *(const float4*)&in[i];
  uint2 o;
  o.x = (unsigned)f2bf(v.x) | ((unsigned)f2bf(v.y) << 16);
  o.y = (unsigned)f2bf(v.z) | ((unsigned)f2bf(v.w) << 16);
  *(uint2*)&out[i] = o;
}

// ---------------- transpose + cast: f32 [R][C] -> bf16 [C][R] ----------------
__global__ void transpose_cast(const float* __restrict__ in, u16* __restrict__ out,
                               int R, int C) {
  __shared__ float tile[64][65];
  int c0 = blockIdx.x * 64, r0 = blockIdx.y * 64;
  int tid = threadIdx.x;
#pragma unroll
  for (int i = 0; i < 16; ++i) {
    int e = i * 256 + tid;
    int rr = e >> 6, cc = e & 63;
    tile[rr][cc] = in[(size_t)(r0 + rr) * C + c0 + cc];
  }
  __syncthreads();
#pragma unroll
  for (int i = 0; i < 16; ++i) {
    int e = i * 256 + tid;
    int oc = e >> 6, orr = e & 63;
    out[(size_t)(c0 + oc) * R + r0 + orr] = f2bf(tile[orr][oc]);
  }
}

// ---------------- GEMM: C[M][N] = A[M][K] * BT[N][K]^T  (bf16 in) ----------------
// 128x128 tile, BK=32, plain dbuf; key-swizzled LDS.
template <typename OUT>
__global__ __launch_bounds__(256)
void gemm_bf16_bt(const u16* __restrict__ A, const u16* __restrict__ BT,
                  OUT* __restrict__ C, int M, int N, int K) {
  __shared__ u16 As[2][128 * 32];
  __shared__ u16 Bs[2][128 * 32];
  int tid = threadIdx.x;
  int row0 = blockIdx.y * 128, col0 = blockIdx.x * 128;
  int wv = tid >> 6, lane = tid & 63, lr = lane & 15, lq = lane >> 4;
  int wm = (wv >> 1) * 64, wn = (wv & 1) * 64;
  f32x4 acc[4][4] = {};

  auto stage = [&](int buf, int ks) {
#pragma unroll
    for (int k = 0; k < 2; ++k) {
      int c = k * 256 + tid;            // 512 chunks/matrix; dest lane-linear
      int row = c >> 2, col = c & 3;
      int key = (row >> 1) & 3;
      async16(&A[(size_t)(row0 + row) * K + ks + (col ^ key) * 8], &As[buf][c * 8]);
      async16(&BT[(size_t)(col0 + row) * K + ks + (col ^ key) * 8], &Bs[buf][c * 8]);
    }
  };

  stage(0, 0);
  __syncthreads();
  int nk = K >> 5;
  for (int t = 0; t < nk; ++t) {
    int cur = t & 1;
    if (t + 1 < nk) stage(cur ^ 1, (t + 1) * 32);

    const char* AsB = (const char*)&As[cur][0];
    const char* BsB = (const char*)&Bs[cur][0];
    bf16x8 a[4], b[4];
#pragma unroll
    for (int mi = 0; mi < 4; ++mi) {
      int row = wm + mi * 16 + lr;
      a[mi] = *(const bf16x8*)(AsB + row * 64 + ((lq ^ ((row >> 1) & 3)) << 4));
    }
#pragma unroll
    for (int ni = 0; ni < 4; ++ni) {
      int row = wn + ni * 16 + lr;
      b[ni] = *(const bf16x8*)(BsB + row * 64 + ((lq ^ ((row >> 1) & 3)) << 4));
    }
#pragma unroll
    for (int mi = 0; mi < 4; ++mi)
#pragma unroll
      for (int ni = 0; ni < 4; ++ni)
        acc[mi][ni] = __builtin_amdgcn_mfma_f32_16x16x32_bf16(a[mi], b[ni], acc[mi][ni], 0, 0, 0);
    __syncthreads();
  }

#pragma unroll
  for (int mi = 0; mi < 4; ++mi)
#pragma unroll
    for (int ni = 0; ni < 4; ++ni)
#pragma unroll
      for (int r = 0; r < 4; ++r) {
        float v = acc[mi][ni][r];
        size_t idx = (size_t)(row0 + wm + mi * 16 + lq * 4 + r) * N + col0 + wn + ni * 16 + lr;
        if constexpr (sizeof(OUT) == 2) C[idx] = (OUT)f2bf(v);
        else                            C[idx] = (OUT)v;
      }
}

// ---------------- RoPE + head-major reorg for Q,K (bf16 qkv input) ----------------
// Q pre-scaled by (1/sqrt(HD)) * log2(e) so softmax uses exp2 directly.
#define SCL2 0.12753224f

__global__ void rope_reorg(const u16* __restrict__ qkv, const int* __restrict__ pos,
                           u16* __restrict__ Qh, u16* __restrict__ Kh) {
  int idx = blockIdx.x * 256 + threadIdx.x;
  if (idx >= T_SEQ * NH * 64) return;
  int d = idx & 63;
  int h = (idx >> 6) & (NH - 1);
  int t = idx >> 10;
  float p = (float)pos[t];
  float inv = exp2f((float)d * -0.20762050594046932f);
  float f = p * inv;
  float s, c;
  __sincosf(f, &s, &c);

  size_t ib = (size_t)t * QKVN + h * HD + d;
  float q1 = bf2f(qkv[ib]), q2 = bf2f(qkv[ib + 64]);
  float k1 = bf2f(qkv[ib + HID]), k2 = bf2f(qkv[ib + HID + 64]);
  size_t ob = ((size_t)h * T_SEQ + t) * HD + d;
  Qh[ob]      = f2bf((q1 * c - q2 * s) * SCL2);
  Qh[ob + 64] = f2bf((q2 * c + q1 * s) * SCL2);
  Kh[ob]      = f2bf(k1 * c - k2 * s);
  Kh[ob + 64] = f2bf(k2 * c + k1 * s);
}

// ---------------- V transpose: qkv v-part bf16 -> Vt bf16 [NH][HD][T] -------------
__global__ void vtrans(const u16* __restrict__ qkv, u16* __restrict__ Vt) {
  __shared__ u16 tile[64][136];   // +8 u16 pad
  int t0 = blockIdx.x * 64;
  int h = blockIdx.y;
  int tid = threadIdx.x;
#pragma unroll
  for (int i = 0; i < 32; ++i) {
    int e = i * 256 + tid;
    int tt = e >> 7, d = e & 127;
    tile[tt][d] = qkv[(size_t)(t0 + tt) * QKVN + 2 * HID + h * HD + d];
  }
  __syncthreads();
#pragma unroll
  for (int i = 0; i < 32; ++i) {
    int e = i * 256 + tid;
    int d = e >> 6, tt = e & 63;
    Vt[((size_t)h * HD + d) * T_SEQ + t0 + tt] = tile[tt][d];
  }
}

// ---------------- causal flash attention v10: v9 + VGPR cap (occupancy lever) ----
// 4 waves/block, Q-tile 128 (32 rows/wave), KVB=32, plain-dbuf __syncthreads.
// __launch_bounds__(256,4): cap VGPR at 128 (the m69 occupancy cliff R4 sat on).
// Swapped-QK^T in-register softmax (R9); acc-rescale guarded by exact sf<1 test.
__global__ __launch_bounds__(256, 4)
void attn_fwd(const u16* __restrict__ Qh, const u16* __restrict__ Kh,
              const u16* __restrict__ Vt, u16* __restrict__ attn) {
  __shared__ u16 Ks[2][32 * 128];   // [kv][d] 256B rows, XOR-8 swizzle
  __shared__ u16 Vs[2][128 * 32];   // [d][kv] 64B rows, key=(row>>1)&3
  __shared__ u16 Ps[4][32 * 36];    // per-wave [q][kv], 72B padded rows

  int tid = threadIdx.x;
  int wv = tid >> 6, lane = tid & 63, lr = lane & 15, lq = lane >> 4;
  // balanced decode: CU-paired blocks get bq and 31-bq
  int id = blockIdx.x;
  int h = id >> 5;
  int bq = (id < 256) ? (id & 31) : 31 - (id & 31);
  int q0 = bq * 128, wrow0 = q0 + wv * 32;
  char* PsB = (char*)&Ps[wv][0];

  // Q fragments (pre-scaled): rows wrow0 + mi*16 + lr, k = kd*32 + lq*8
  bf16x8 qf[2][4];
#pragma unroll
  for (int mi = 0; mi < 2; ++mi)
#pragma unroll
    for (int kd = 0; kd < 4; ++kd)
      qf[mi][kd] = *(const bf16x8*)
          &Qh[((size_t)h * T_SEQ + wrow0 + mi * 16 + lr) * HD + kd * 32 + lq * 8];

  f32x4 acc_o[2][8] = {};
  float m_run[2] = {-1e30f, -1e30f};
  float l_run[2] = {0.0f, 0.0f};

  auto stage = [&](int buf, int jb) {
#pragma unroll
    for (int k = 0; k < 2; ++k) {      // K tile: 512 chunks, 16/row, src pre-swz
      int c = k * 256 + tid;
      int row = c >> 4;
      int sc = (c ^ (row & 7)) & 15;
      async16(&Kh[((size_t)h * T_SEQ + jb + row) * HD + sc * 8], &Ks[buf][c * 8]);
    }
#pragma unroll
    for (int k = 0; k < 2; ++k) {      // V tile: 512 chunks, 4/row, key-swz
      int c = k * 256 + tid;
      int row = c >> 2, col = c & 3;
      int key = (row >> 1) & 3;
      async16(&Vt[((size_t)h * HD + row) * T_SEQ + jb + (col ^ key) * 8],
              &Vs[buf][c * 8]);
    }
  };

  int nt = bq * 4 + 4;
  stage(0, 0);
  __syncthreads();

  for (int j = 0; j < nt; ++j) {
    int cur = j & 1;
    int jb = j * KVB;
    if (j + 1 < nt) stage(cur ^ 1, jb + KVB);

    if (jb <= wrow0 + 31) {
      const char* KsB = (const char*)&Ks[cur][0];
      const char* VsB = (const char*)&Vs[cur][0];

      // ---- S^T = K Q^T  (swapped operands; st[kj][qi]: col=q_local=lr,
      //      row = k_local = lq*4 + r) ----
      f32x4 st[2][2] = {};
#pragma unroll
      for (int kd = 0; kd < 4; ++kd) {
#pragma unroll
        for (int kj = 0; kj < 2; ++kj) {
          int row = kj * 16 + lr;
          int byt = (row << 8) + kd * 64 + lq * 16;
          bf16x8 kf = *(const bf16x8*)(KsB + (byt ^ ((row & 7) << 4)));
#pragma unroll
          for (int qi = 0; qi < 2; ++qi)
            st[kj][qi] = __builtin_amdgcn_mfma_f32_16x16x32_bf16(
                kf, qf[qi][kd], st[kj][qi], 0, 0, 0);
        }
      }

      // ---- causal mask (wave-uniform branch; all in-lane) ----
      if (jb + KVB - 1 > wrow0) {
#pragma unroll
        for (int qi = 0; qi < 2; ++qi) {
          int qg = wrow0 + qi * 16 + lr;
#pragma unroll
          for (int kj = 0; kj < 2; ++kj)
#pragma unroll
            for (int r = 0; r < 4; ++r)
              if (jb + kj * 16 + lq * 4 + r > qg) st[kj][qi][r] = -1e30f;
        }
      }

      // ---- in-register softmax per q-column ----
      float sf[2];
#pragma unroll
      for (int qi = 0; qi < 2; ++qi) {
        float mx = fmaxf(fmaxf(fmaxf(st[0][qi][0], st[0][qi][1]),
                               fmaxf(st[0][qi][2], st[0][qi][3])),
                         fmaxf(fmaxf(st[1][qi][0], st[1][qi][1]),
                               fmaxf(st[1][qi][2], st[1][qi][3])));
        mx = fmaxf(mx, __shfl_xor(mx, 16));
        mx = fmaxf(mx, __shfl_xor(mx, 32));
        float mnew = fmaxf(m_run[qi], mx);
        sf[qi] = exp2f(m_run[qi] - mnew);
        m_run[qi] = mnew;

        float rs = 0.0f;
#pragma unroll
        for (int kj = 0; kj < 2; ++kj) {
          float p0 = exp2f(st[kj][qi][0] - mnew);
          float p1 = exp2f(st[kj][qi][1] - mnew);
          float p2 = exp2f(st[kj][qi][2] - mnew);
          float p3 = exp2f(st[kj][qi][3] - mnew);
          rs += (p0 + p1) + (p2 + p3);
          uint2 w;
          w.x = (u32)f2bf(p0) | ((u32)f2bf(p1) << 16);
          w.y = (u32)f2bf(p2) | ((u32)f2bf(p3) << 16);
          *(uint2*)(PsB + (qi * 16 + lr) * 72 + (kj * 16 + lq * 4) * 2) = w;
        }
        l_run[qi] = l_run[qi] * sf[qi] + rs;   // per-lane partial l
      }

      // ---- rescale O only when some max grew (exact: sf==1 otherwise) ----
      if (__any((sf[0] < 1.0f) || (sf[1] < 1.0f))) {
#pragma unroll
        for (int mi = 0; mi < 2; ++mi) {
          float sfb[4];
#pragma unroll
          for (int r = 0; r < 4; ++r) sfb[r] = __shfl(sf[mi], lq * 4 + r);
#pragma unroll
          for (int nd = 0; nd < 8; ++nd)
#pragma unroll
            for (int r = 0; r < 4; ++r) acc_o[mi][nd][r] *= sfb[r];
        }
      }

      // ---- O += P V  (32 x 128, K=32) ----
#pragma unroll
      for (int mi = 0; mi < 2; ++mi) {
        bf16x8 pa = *(const bf16x8*)(PsB + (mi * 16 + lr) * 72 + lq * 16);
#pragma unroll
        for (int nd = 0; nd < 8; ++nd) {
          int vrow = nd * 16 + lr;
          bf16x8 vb = *(const bf16x8*)(VsB + vrow * 64 + ((lq ^ ((vrow >> 1) & 3)) << 4));
          acc_o[mi][nd] = __builtin_amdgcn_mfma_f32_16x16x32_bf16(
              pa, vb, acc_o[mi][nd], 0, 0, 0);
        }
      }
    }
    __syncthreads();
  }

  // epilogue: reduce per-lane partial l, broadcast to acc layout, store
#pragma unroll
  for (int mi = 0; mi < 2; ++mi) {
    float lred = l_run[mi];
    lred += __shfl_xor(lred, 16);
    lred += __shfl_xor(lred, 32);
    float rlb[4];
#pragma unroll
    for (int r = 0; r < 4; ++r) rlb[r] = 1.0f / __shfl(lred, lq * 4 + r);
#pragma unroll
    for (int r = 0; r < 4; ++r) {
      int qrow = wrow0 + mi * 16 + lq * 4 + r;
#pragma unroll
      for (int nd = 0; nd < 8; ++nd)
        attn[(size_t)qrow * HID + h * HD + nd * 16 + lr] = f2bf(acc_o[mi][nd][r] * rlb[r]);
    }
  }
}

extern "C" void kernel_launch(void* const* d_in, const int* in_sizes, int n_in,
                              void* d_out, int out_size, void* d_ws, size_t ws_size,
                              hipStream_t stream) {
  const float* hidden    = (const float*)d_in[0];
  const int*   positions = (const int*)d_in[1];
  const float* w_qkv     = (const float*)d_in[2];
  const float* w_o       = (const float*)d_in[3];
  float* out = (float*)d_out;

  char* p = (char*)d_ws;
  u16* hs_b   = (u16*)p;  p += (size_t)T_SEQ * HID * 2;
  u16* wqkvT  = (u16*)p;  p += (size_t)QKVN * HID * 2;
  u16* woT    = (u16*)p;  p += (size_t)HID * HID * 2;
  u16* qkvb   = (u16*)p;  p += (size_t)T_SEQ * QKVN * 2;
  u16* Qh     = (u16*)p;  p += (size_t)T_SEQ * HID * 2;
  u16* Kh     = (u16*)p;  p += (size_t)T_SEQ * HID * 2;
  u16* Vt     = (u16*)p;  p += (size_t)T_SEQ * HID * 2;
  u16* attn_b = (u16*)p;  p += (size_t)T_SEQ * HID * 2;

  cast_f32_bf16<<<(T_SEQ * HID / 4 + 255) / 256, 256, 0, stream>>>(hidden, hs_b, T_SEQ * HID);
  transpose_cast<<<dim3(QKVN / 64, HID / 64), 256, 0, stream>>>(w_qkv, wqkvT, HID, QKVN);
  transpose_cast<<<dim3(HID / 64, HID / 64), 256, 0, stream>>>(w_o, woT, HID, HID);
  gemm_bf16_bt<u16><<<dim3(QKVN / 128, T_SEQ / 128), 256, 0, stream>>>(hs_b, wqkvT, qkvb,
                                                                       T_SEQ, QKVN, HID);
  rope_reorg<<<(T_SEQ * NH * 64 + 255) / 256, 256, 0, stream>>>(qkvb, positions, Qh, Kh);
  vtrans<<<dim3(T_SEQ / 64, NH), 256, 0, stream>>>(qkvb, Vt);
  attn_fwd<<<512, 256, 0, stream>>>(Qh, Kh, Vt, attn_b);
  gemm_bf16_bt<float><<<dim3(HID / 128, T_SEQ / 128), 256, 0, stream>>>(attn_b, woT, out,
                                                                        T_SEQ, HID, HID);
}

// Round 11
// 553.385 us; speedup vs baseline: 1.1399x; 1.1399x over previous
//
#include <hip/hip_runtime.h>
#include <hip/hip_bf16.h>
#include <cstdint>
#include <cstddef>

#define T_SEQ 4096
#define HID   2048
#define NH    16
#define HD    128
#define QKVN  6144
#define KVB   32

typedef unsigned short u16;
typedef unsigned int u32;
typedef __bf16 bf16x8 __attribute__((ext_vector_type(8)));
typedef float  f32x4  __attribute__((ext_vector_type(4)));

typedef const __attribute__((address_space(1))) void* gas_ptr;
typedef __attribute__((address_space(3))) void* las_ptr;

__device__ __forceinline__ void async16(const void* g, void* l) {
  __builtin_amdgcn_global_load_lds((gas_ptr)g, (las_ptr)l, 16, 0, 0);
}

__device__ __forceinline__ u16 f2bf(float f) {
  unsigned int u = __float_as_uint(f);
  u += 0x7fffu + ((u >> 16) & 1u);
  return (u16)(u >> 16);
}

__device__ __forceinline__ float bf2f(u16 x) {
  return __uint_as_float((unsigned)x << 16);
}

// ---------------- elementwise cast f32 -> bf16 ----------------
__global__ void cast_f32_bf16(const float* __restrict__ in, u16* __restrict__ out, int n) {
  int i = (blockIdx.x * blockDim.x + threadIdx.x) * 4;
  if (i >= n) return;
  float4 v = *(const float4*)&in[i];
  uint2 o;
  o.x = (unsigned)f2bf(v.x) | ((unsigned)f2bf(v.y) << 16);
  o.y = (unsigned)f2bf(v.z) | ((unsigned)f2bf(v.w) << 16);
  *(uint2*)&out[i] = o;
}

// ---------------- transpose + cast: f32 [R][C] -> bf16 [C][R] ----------------
__global__ void transpose_cast(const float* __restrict__ in, u16* __restrict__ out,
                               int R, int C) {
  __shared__ float tile[64][65];
  int c0 = blockIdx.x * 64, r0 = blockIdx.y * 64;
  int tid = threadIdx.x;
#pragma unroll
  for (int i = 0; i < 16; ++i) {
    int e = i * 256 + tid;
    int rr = e >> 6, cc = e & 63;
    tile[rr][cc] = in[(size_t)(r0 + rr) * C + c0 + cc];
  }
  __syncthreads();
#pragma unroll
  for (int i = 0; i < 16; ++i) {
    int e = i * 256 + tid;
    int oc = e >> 6, orr = e & 63;
    out[(size_t)(c0 + oc) * R + r0 + orr] = f2bf(tile[orr][oc]);
  }
}

// ---------------- GEMM: C[M][N] = A[M][K] * BT[N][K]^T  (bf16 in) ----------------
// 128x128 tile, BK=32, plain dbuf; key-swizzled LDS.
template <typename OUT>
__global__ __launch_bounds__(256)
void gemm_bf16_bt(const u16* __restrict__ A, const u16* __restrict__ BT,
                  OUT* __restrict__ C, int M, int N, int K) {
  __shared__ u16 As[2][128 * 32];
  __shared__ u16 Bs[2][128 * 32];
  int tid = threadIdx.x;
  int row0 = blockIdx.y * 128, col0 = blockIdx.x * 128;
  int wv = tid >> 6, lane = tid & 63, lr = lane & 15, lq = lane >> 4;
  int wm = (wv >> 1) * 64, wn = (wv & 1) * 64;
  f32x4 acc[4][4] = {};

  auto stage = [&](int buf, int ks) {
#pragma unroll
    for (int k = 0; k < 2; ++k) {
      int c = k * 256 + tid;            // 512 chunks/matrix; dest lane-linear
      int row = c >> 2, col = c & 3;
      int key = (row >> 1) & 3;
      async16(&A[(size_t)(row0 + row) * K + ks + (col ^ key) * 8], &As[buf][c * 8]);
      async16(&BT[(size_t)(col0 + row) * K + ks + (col ^ key) * 8], &Bs[buf][c * 8]);
    }
  };

  stage(0, 0);
  __syncthreads();
  int nk = K >> 5;
  for (int t = 0; t < nk; ++t) {
    int cur = t & 1;
    if (t + 1 < nk) stage(cur ^ 1, (t + 1) * 32);

    const char* AsB = (const char*)&As[cur][0];
    const char* BsB = (const char*)&Bs[cur][0];
    bf16x8 a[4], b[4];
#pragma unroll
    for (int mi = 0; mi < 4; ++mi) {
      int row = wm + mi * 16 + lr;
      a[mi] = *(const bf16x8*)(AsB + row * 64 + ((lq ^ ((row >> 1) & 3)) << 4));
    }
#pragma unroll
    for (int ni = 0; ni < 4; ++ni) {
      int row = wn + ni * 16 + lr;
      b[ni] = *(const bf16x8*)(BsB + row * 64 + ((lq ^ ((row >> 1) & 3)) << 4));
    }
#pragma unroll
    for (int mi = 0; mi < 4; ++mi)
#pragma unroll
      for (int ni = 0; ni < 4; ++ni)
        acc[mi][ni] = __builtin_amdgcn_mfma_f32_16x16x32_bf16(a[mi], b[ni], acc[mi][ni], 0, 0, 0);
    __syncthreads();
  }

#pragma unroll
  for (int mi = 0; mi < 4; ++mi)
#pragma unroll
    for (int ni = 0; ni < 4; ++ni)
#pragma unroll
      for (int r = 0; r < 4; ++r) {
        float v = acc[mi][ni][r];
        size_t idx = (size_t)(row0 + wm + mi * 16 + lq * 4 + r) * N + col0 + wn + ni * 16 + lr;
        if constexpr (sizeof(OUT) == 2) C[idx] = (OUT)f2bf(v);
        else                            C[idx] = (OUT)v;
      }
}

// ---------------- RoPE + head-major reorg for Q,K (bf16 qkv input) ----------------
// Q pre-scaled by (1/sqrt(HD)) * log2(e) so softmax uses exp2 directly.
#define SCL2 0.12753224f

__global__ void rope_reorg(const u16* __restrict__ qkv, const int* __restrict__ pos,
                           u16* __restrict__ Qh, u16* __restrict__ Kh) {
  int idx = blockIdx.x * 256 + threadIdx.x;
  if (idx >= T_SEQ * NH * 64) return;
  int d = idx & 63;
  int h = (idx >> 6) & (NH - 1);
  int t = idx >> 10;
  float p = (float)pos[t];
  float inv = exp2f((float)d * -0.20762050594046932f);
  float f = p * inv;
  float s, c;
  __sincosf(f, &s, &c);

  size_t ib = (size_t)t * QKVN + h * HD + d;
  float q1 = bf2f(qkv[ib]), q2 = bf2f(qkv[ib + 64]);
  float k1 = bf2f(qkv[ib + HID]), k2 = bf2f(qkv[ib + HID + 64]);
  size_t ob = ((size_t)h * T_SEQ + t) * HD + d;
  Qh[ob]      = f2bf((q1 * c - q2 * s) * SCL2);
  Qh[ob + 64] = f2bf((q2 * c + q1 * s) * SCL2);
  Kh[ob]      = f2bf(k1 * c - k2 * s);
  Kh[ob + 64] = f2bf(k2 * c + k1 * s);
}

// ---------------- V transpose: qkv v-part bf16 -> Vt bf16 [NH][HD][T] -------------
__global__ void vtrans(const u16* __restrict__ qkv, u16* __restrict__ Vt) {
  __shared__ u16 tile[64][136];   // +8 u16 pad
  int t0 = blockIdx.x * 64;
  int h = blockIdx.y;
  int tid = threadIdx.x;
#pragma unroll
  for (int i = 0; i < 32; ++i) {
    int e = i * 256 + tid;
    int tt = e >> 7, d = e & 127;
    tile[tt][d] = qkv[(size_t)(t0 + tt) * QKVN + 2 * HID + h * HD + d];
  }
  __syncthreads();
#pragma unroll
  for (int i = 0; i < 32; ++i) {
    int e = i * 256 + tid;
    int d = e >> 6, tt = e & 63;
    Vt[((size_t)h * HD + d) * T_SEQ + t0 + tt] = tile[tt][d];
  }
}

// ---------------- causal flash attention v11: R4 body + KV-split x2 --------------
// 1024 blocks = (h, bq, split s). Each block runs R4's proven loop over HALF of
// bq's KV tiles, writing unnormalized f32 O-partial + per-row (m,l). A combine
// kernel merges the two splits. 4 waves, Q-tile 128, KVB=32, 40KB LDS ->
// 4 blocks/CU resident (TLP 2x vs R4's grid-limited 2/CU).
__global__ __launch_bounds__(256)
void attn_fwd(const u16* __restrict__ Qh, const u16* __restrict__ Kh,
              const u16* __restrict__ Vt, float* __restrict__ Opart,
              float2* __restrict__ ml) {
  __shared__ u16 Ks[2][32 * 128];   // [kv][d] 256B rows, XOR-8 swizzle
  __shared__ u16 Vs[2][128 * 32];   // [d][kv] 64B rows, linear
  __shared__ u16 Ps[4][32 * 32];    // per-wave [q][kv] 64B rows, linear

  int tid = threadIdx.x;
  int wv = tid >> 6, lane = tid & 63, lr = lane & 15, lq = lane >> 4;
  // CU-quad decode: {(gs,s0),(31-gs,s0),(gs,s1),(31-gs,s1)} -> constant work/CU,
  // same h across the quad for KV L2 sharing.
  int id = blockIdx.x;
  int g = id & 255, quad = id >> 8;
  int h = g >> 4, gs = g & 15;
  int bq = (quad & 1) ? (31 - gs) : gs;
  int s = quad >> 1;
  int q0 = bq * 128, wrow0 = q0 + wv * 32;

  // Q fragments (pre-scaled): rows wrow0 + mi*16 + lr, k = kd*32 + lq*8
  bf16x8 qf[2][4];
#pragma unroll
  for (int mi = 0; mi < 2; ++mi)
#pragma unroll
    for (int kd = 0; kd < 4; ++kd)
      qf[mi][kd] = *(const bf16x8*)
          &Qh[((size_t)h * T_SEQ + wrow0 + mi * 16 + lr) * HD + kd * 32 + lq * 8];

  f32x4 acc_o[2][8] = {};
  float m_run[2][4], l_run[2][4];
#pragma unroll
  for (int mi = 0; mi < 2; ++mi)
#pragma unroll
    for (int r = 0; r < 4; ++r) { m_run[mi][r] = -1e30f; l_run[mi][r] = 0.0f; }

  auto stage = [&](int buf, int jb) {
#pragma unroll
    for (int k = 0; k < 2; ++k) {      // K tile: 512 chunks, 16/row, src pre-swz
      int c = k * 256 + tid;
      int row = c >> 4;
      int sc = (c ^ (row & 7)) & 15;
      async16(&Kh[((size_t)h * T_SEQ + jb + row) * HD + sc * 8], &Ks[buf][c * 8]);
    }
#pragma unroll
    for (int k = 0; k < 2; ++k) {      // V tile: 512 chunks, 4/row, linear
      int c = k * 256 + tid;
      int row = c >> 2, col = c & 3;
      async16(&Vt[((size_t)h * HD + row) * T_SEQ + jb + col * 8], &Vs[buf][c * 8]);
    }
  };

  int ntt = 2 * bq + 2;                // tiles per split
  int j0 = s * ntt, j1 = j0 + ntt;
  stage(0, j0 * KVB);
  __syncthreads();

  for (int j = j0; j < j1; ++j) {
    int cur = (j - j0) & 1;
    int jb = j * KVB;
    if (j + 1 < j1) stage(cur ^ 1, jb + KVB);

    if (jb <= wrow0 + 31) {
      const char* KsB = (const char*)&Ks[cur][0];

      // ---- S = Q K^T  (32 x 32) ----
      f32x4 s_acc[2][2] = {};
#pragma unroll
      for (int kd = 0; kd < 4; ++kd) {
#pragma unroll
        for (int nj = 0; nj < 2; ++nj) {
          int row = nj * 16 + lr;
          int byt = (row << 8) + kd * 64 + lq * 16;
          bf16x8 kf = *(const bf16x8*)(KsB + (byt ^ ((row & 7) << 4)));
#pragma unroll
          for (int mi = 0; mi < 2; ++mi)
            s_acc[mi][nj] = __builtin_amdgcn_mfma_f32_16x16x32_bf16(
                qf[mi][kd], kf, s_acc[mi][nj], 0, 0, 0);
        }
      }

      bool diag = (jb + KVB - 1 > wrow0);
      // ---- online softmax (R4 pattern) ----
#pragma unroll
      for (int mi = 0; mi < 2; ++mi) {
        float pm[4];
#pragma unroll
        for (int r = 0; r < 4; ++r) {
          int qrow = wrow0 + mi * 16 + lq * 4 + r;
          float mx = -1e30f;
#pragma unroll
          for (int nj = 0; nj < 2; ++nj) {
            float sv = s_acc[mi][nj][r];
            if (diag && (jb + nj * 16 + lr > qrow)) sv = -1e30f;
            s_acc[mi][nj][r] = sv;
            mx = fmaxf(mx, sv);
          }
          pm[r] = mx;
        }
#pragma unroll
        for (int r = 0; r < 4; ++r) {
          pm[r] = fmaxf(pm[r], __shfl_xor(pm[r], 1));
          pm[r] = fmaxf(pm[r], __shfl_xor(pm[r], 2));
          pm[r] = fmaxf(pm[r], __shfl_xor(pm[r], 4));
          pm[r] = fmaxf(pm[r], __shfl_xor(pm[r], 8));
        }
#pragma unroll
        for (int r = 0; r < 4; ++r) {
          float mnew = fmaxf(m_run[mi][r], pm[r]);
          float sf = exp2f(m_run[mi][r] - mnew);
          m_run[mi][r] = mnew;
          int prow = mi * 16 + lq * 4 + r;
          float rs = 0.0f;
#pragma unroll
          for (int nj = 0; nj < 2; ++nj) {
            float p = exp2f(s_acc[mi][nj][r] - mnew);
            rs += p;
            Ps[wv][prow * 32 + nj * 16 + lr] = f2bf(p);
          }
          rs += __shfl_xor(rs, 1);
          rs += __shfl_xor(rs, 2);
          rs += __shfl_xor(rs, 4);
          rs += __shfl_xor(rs, 8);
          l_run[mi][r] = l_run[mi][r] * sf + rs;
#pragma unroll
          for (int nd = 0; nd < 8; ++nd) acc_o[mi][nd][r] *= sf;
        }
      }

      // ---- O += P V  (32 x 128, K=32) ----
#pragma unroll
      for (int mi = 0; mi < 2; ++mi) {
        bf16x8 pa = *(const bf16x8*)&Ps[wv][(mi * 16 + lr) * 32 + lq * 8];
#pragma unroll
        for (int nd = 0; nd < 8; ++nd) {
          bf16x8 vb = *(const bf16x8*)&Vs[cur][(nd * 16 + lr) * 32 + lq * 8];
          acc_o[mi][nd] = __builtin_amdgcn_mfma_f32_16x16x32_bf16(
              pa, vb, acc_o[mi][nd], 0, 0, 0);
        }
      }
    }
    __syncthreads();
  }

  // epilogue: unnormalized O-partial (f32) + per-row (m,l)
  float* Op = Opart + (size_t)s * T_SEQ * HID;
#pragma unroll
  for (int mi = 0; mi < 2; ++mi)
#pragma unroll
    for (int r = 0; r < 4; ++r) {
      int qrow = wrow0 + mi * 16 + lq * 4 + r;
#pragma unroll
      for (int nd = 0; nd < 8; ++nd)
        Op[(size_t)qrow * HID + h * HD + nd * 16 + lr] = acc_o[mi][nd][r];
      if (lr == 0)
        ml[((size_t)s * NH + h) * T_SEQ + qrow] = make_float2(m_run[mi][r], l_run[mi][r]);
    }
}

// ---------------- combine: merge KV-split partials -> bf16 attn ------------------
__global__ __launch_bounds__(256)
void attn_combine(const float* __restrict__ Opart, const float2* __restrict__ ml,
                  u16* __restrict__ attn) {
  int idx = blockIdx.x * 256 + threadIdx.x;      // T*HID/4 quads
  int e4 = idx * 4;
  int qrow = e4 >> 11;                            // / HID
  int col = e4 & (HID - 1);
  int h = col >> 7;
  float2 a = ml[(size_t)h * T_SEQ + qrow];
  float2 b = ml[((size_t)NH + h) * T_SEQ + qrow];
  float m = fmaxf(a.x, b.x);
  float w0 = exp2f(a.x - m), w1 = exp2f(b.x - m);
  float rl = 1.0f / (a.y * w0 + b.y * w1);
  float4 o0 = *(const float4*)&Opart[(size_t)qrow * HID + col];
  float4 o1 = *(const float4*)&Opart[(size_t)T_SEQ * HID + (size_t)qrow * HID + col];
  uint2 o;
  o.x = (u32)f2bf((o0.x * w0 + o1.x * w1) * rl) |
        ((u32)f2bf((o0.y * w0 + o1.y * w1) * rl) << 16);
  o.y = (u32)f2bf((o0.z * w0 + o1.z * w1) * rl) |
        ((u32)f2bf((o0.w * w0 + o1.w * w1) * rl) << 16);
  *(uint2*)&attn[e4] = o;
}

extern "C" void kernel_launch(void* const* d_in, const int* in_sizes, int n_in,
                              void* d_out, int out_size, void* d_ws, size_t ws_size,
                              hipStream_t stream) {
  const float* hidden    = (const float*)d_in[0];
  const int*   positions = (const int*)d_in[1];
  const float* w_qkv     = (const float*)d_in[2];
  const float* w_o       = (const float*)d_in[3];
  float* out = (float*)d_out;

  char* p = (char*)d_ws;
  u16* woT    = (u16*)p;  p += (size_t)HID * HID * 2;
  u16* Qh     = (u16*)p;  p += (size_t)T_SEQ * HID * 2;
  u16* Kh     = (u16*)p;  p += (size_t)T_SEQ * HID * 2;
  u16* Vt     = (u16*)p;  p += (size_t)T_SEQ * HID * 2;
  u16* attn_b = (u16*)p;  p += (size_t)T_SEQ * HID * 2;
  float2* ml  = (float2*)p; p += (size_t)2 * NH * T_SEQ * sizeof(float2);
  // union region: {hs_b, wqkvT, qkvb} (live until vtrans) overlaps Opart
  // (written by attn_fwd, strictly later in stream order).
  char* un = p;
  u16* hs_b   = (u16*)un;
  u16* wqkvT  = (u16*)(un + (size_t)T_SEQ * HID * 2);
  u16* qkvb   = (u16*)(un + (size_t)T_SEQ * HID * 2 + (size_t)QKVN * HID * 2);
  float* Opart = (float*)un;

  cast_f32_bf16<<<(T_SEQ * HID / 4 + 255) / 256, 256, 0, stream>>>(hidden, hs_b, T_SEQ * HID);
  transpose_cast<<<dim3(QKVN / 64, HID / 64), 256, 0, stream>>>(w_qkv, wqkvT, HID, QKVN);
  transpose_cast<<<dim3(HID / 64, HID / 64), 256, 0, stream>>>(w_o, woT, HID, HID);
  gemm_bf16_bt<u16><<<dim3(QKVN / 128, T_SEQ / 128), 256, 0, stream>>>(hs_b, wqkvT, qkvb,
                                                                       T_SEQ, QKVN, HID);
  rope_reorg<<<(T_SEQ * NH * 64 + 255) / 256, 256, 0, stream>>>(qkvb, positions, Qh, Kh);
  vtrans<<<dim3(T_SEQ / 64, NH), 256, 0, stream>>>(qkvb, Vt);
  attn_fwd<<<1024, 256, 0, stream>>>(Qh, Kh, Vt, Opart, ml);
  attn_combine<<<T_SEQ * HID / 4 / 256, 256, 0, stream>>>(Opart, ml, attn_b);
  gemm_bf16_bt<float><<<dim3(HID / 128, T_SEQ / 128), 256, 0, stream>>>(attn_b, woT, out,
                                                                        T_SEQ, HID, HID);
}

// Round 12
// 498.019 us; speedup vs baseline: 1.2666x; 1.1112x over previous
//
#include <hip/hip_runtime.h>
#include <hip/hip_bf16.h>
#include <cstdint>
#include <cstddef>

#define T_SEQ 4096
#define HID   2048
#define NH    16
#define HD    128
#define QKVN  6144
#define KVB   32
#define CHT   16          // KV tiles per chunk
#define CPH   144         // chunks per head

typedef unsigned short u16;
typedef unsigned int u32;
typedef __bf16 bf16x8 __attribute__((ext_vector_type(8)));
typedef float  f32x4  __attribute__((ext_vector_type(4)));

typedef const __attribute__((address_space(1))) void* gas_ptr;
typedef __attribute__((address_space(3))) void* las_ptr;

__device__ __forceinline__ void async16(const void* g, void* l) {
  __builtin_amdgcn_global_load_lds((gas_ptr)g, (las_ptr)l, 16, 0, 0);
}

__device__ __forceinline__ u16 f2bf(float f) {
  unsigned int u = __float_as_uint(f);
  u += 0x7fffu + ((u >> 16) & 1u);
  return (u16)(u >> 16);
}

__device__ __forceinline__ float bf2f(u16 x) {
  return __uint_as_float((unsigned)x << 16);
}

// ---------------- elementwise cast f32 -> bf16 ----------------
__global__ void cast_f32_bf16(const float* __restrict__ in, u16* __restrict__ out, int n) {
  int i = (blockIdx.x * blockDim.x + threadIdx.x) * 4;
  if (i >= n) return;
  float4 v = *(const float4*)&in[i];
  uint2 o;
  o.x = (unsigned)f2bf(v.x) | ((unsigned)f2bf(v.y) << 16);
  o.y = (unsigned)f2bf(v.z) | ((unsigned)f2bf(v.w) << 16);
  *(uint2*)&out[i] = o;
}

// ---------------- transpose + cast: f32 [R][C] -> bf16 [C][R] ----------------
__global__ void transpose_cast(const float* __restrict__ in, u16* __restrict__ out,
                               int R, int C) {
  __shared__ float tile[64][65];
  int c0 = blockIdx.x * 64, r0 = blockIdx.y * 64;
  int tid = threadIdx.x;
#pragma unroll
  for (int i = 0; i < 16; ++i) {
    int e = i * 256 + tid;
    int rr = e >> 6, cc = e & 63;
    tile[rr][cc] = in[(size_t)(r0 + rr) * C + c0 + cc];
  }
  __syncthreads();
#pragma unroll
  for (int i = 0; i < 16; ++i) {
    int e = i * 256 + tid;
    int oc = e >> 6, orr = e & 63;
    out[(size_t)(c0 + oc) * R + r0 + orr] = f2bf(tile[orr][oc]);
  }
}

// ---------------- GEMM: C[M][N] = A[M][K] * BT[N][K]^T  (bf16 in) ----------------
// 128x128 tile, BK=32, plain dbuf; key-swizzled LDS.
template <typename OUT>
__global__ __launch_bounds__(256)
void gemm_bf16_bt(const u16* __restrict__ A, const u16* __restrict__ BT,
                  OUT* __restrict__ C, int M, int N, int K) {
  __shared__ u16 As[2][128 * 32];
  __shared__ u16 Bs[2][128 * 32];
  int tid = threadIdx.x;
  int row0 = blockIdx.y * 128, col0 = blockIdx.x * 128;
  int wv = tid >> 6, lane = tid & 63, lr = lane & 15, lq = lane >> 4;
  int wm = (wv >> 1) * 64, wn = (wv & 1) * 64;
  f32x4 acc[4][4] = {};

  auto stage = [&](int buf, int ks) {
#pragma unroll
    for (int k = 0; k < 2; ++k) {
      int c = k * 256 + tid;            // 512 chunks/matrix; dest lane-linear
      int row = c >> 2, col = c & 3;
      int key = (row >> 1) & 3;
      async16(&A[(size_t)(row0 + row) * K + ks + (col ^ key) * 8], &As[buf][c * 8]);
      async16(&BT[(size_t)(col0 + row) * K + ks + (col ^ key) * 8], &Bs[buf][c * 8]);
    }
  };

  stage(0, 0);
  __syncthreads();
  int nk = K >> 5;
  for (int t = 0; t < nk; ++t) {
    int cur = t & 1;
    if (t + 1 < nk) stage(cur ^ 1, (t + 1) * 32);

    const char* AsB = (const char*)&As[cur][0];
    const char* BsB = (const char*)&Bs[cur][0];
    bf16x8 a[4], b[4];
#pragma unroll
    for (int mi = 0; mi < 4; ++mi) {
      int row = wm + mi * 16 + lr;
      a[mi] = *(const bf16x8*)(AsB + row * 64 + ((lq ^ ((row >> 1) & 3)) << 4));
    }
#pragma unroll
    for (int ni = 0; ni < 4; ++ni) {
      int row = wn + ni * 16 + lr;
      b[ni] = *(const bf16x8*)(BsB + row * 64 + ((lq ^ ((row >> 1) & 3)) << 4));
    }
#pragma unroll
    for (int mi = 0; mi < 4; ++mi)
#pragma unroll
      for (int ni = 0; ni < 4; ++ni)
        acc[mi][ni] = __builtin_amdgcn_mfma_f32_16x16x32_bf16(a[mi], b[ni], acc[mi][ni], 0, 0, 0);
    __syncthreads();
  }

#pragma unroll
  for (int mi = 0; mi < 4; ++mi)
#pragma unroll
    for (int ni = 0; ni < 4; ++ni)
#pragma unroll
      for (int r = 0; r < 4; ++r) {
        float v = acc[mi][ni][r];
        size_t idx = (size_t)(row0 + wm + mi * 16 + lq * 4 + r) * N + col0 + wn + ni * 16 + lr;
        if constexpr (sizeof(OUT) == 2) C[idx] = (OUT)f2bf(v);
        else                            C[idx] = (OUT)v;
      }
}

// ---------------- RoPE + head-major reorg for Q,K (bf16 qkv input) ----------------
// Q pre-scaled by (1/sqrt(HD)) * log2(e) so softmax uses exp2 directly.
#define SCL2 0.12753224f

__global__ void rope_reorg(const u16* __restrict__ qkv, const int* __restrict__ pos,
                           u16* __restrict__ Qh, u16* __restrict__ Kh) {
  int idx = blockIdx.x * 256 + threadIdx.x;
  if (idx >= T_SEQ * NH * 64) return;
  int d = idx & 63;
  int h = (idx >> 6) & (NH - 1);
  int t = idx >> 10;
  float p = (float)pos[t];
  float inv = exp2f((float)d * -0.20762050594046932f);
  float f = p * inv;
  float s, c;
  __sincosf(f, &s, &c);

  size_t ib = (size_t)t * QKVN + h * HD + d;
  float q1 = bf2f(qkv[ib]), q2 = bf2f(qkv[ib + 64]);
  float k1 = bf2f(qkv[ib + HID]), k2 = bf2f(qkv[ib + HID + 64]);
  size_t ob = ((size_t)h * T_SEQ + t) * HD + d;
  Qh[ob]      = f2bf((q1 * c - q2 * s) * SCL2);
  Qh[ob + 64] = f2bf((q2 * c + q1 * s) * SCL2);
  Kh[ob]      = f2bf(k1 * c - k2 * s);
  Kh[ob + 64] = f2bf(k2 * c + k1 * s);
}

// ---------------- V transpose: qkv v-part bf16 -> Vt bf16 [NH][HD][T] -------------
__global__ void vtrans(const u16* __restrict__ qkv, u16* __restrict__ Vt) {
  __shared__ u16 tile[64][136];   // +8 u16 pad
  int t0 = blockIdx.x * 64;
  int h = blockIdx.y;
  int tid = threadIdx.x;
#pragma unroll
  for (int i = 0; i < 32; ++i) {
    int e = i * 256 + tid;
    int tt = e >> 7, d = e & 127;
    tile[tt][d] = qkv[(size_t)(t0 + tt) * QKVN + 2 * HID + h * HD + d];
  }
  __syncthreads();
#pragma unroll
  for (int i = 0; i < 32; ++i) {
    int e = i * 256 + tid;
    int d = e >> 6, tt = e & 63;
    Vt[((size_t)h * HD + d) * T_SEQ + t0 + tt] = tile[tt][d];
  }
}

// ---------------- causal flash attention v12: R4 body + uniform 16-tile chunks ---
// 2304 blocks = (h, bq, chunk). Every block does <=16 KV-tile iterations ->
// uniform durations -> dynamic refill keeps ~4 blocks/CU resident all kernel.
// Partials: bf16 unnormalized O + per-row (m,l); combine merges <=8 chunks.
__global__ __launch_bounds__(256)
void attn_fwd(const u16* __restrict__ Qh, const u16* __restrict__ Kh,
              const u16* __restrict__ Vt, u16* __restrict__ Opart,
              float2* __restrict__ ml) {
  __shared__ u16 Ks[2][32 * 128];   // [kv][d] 256B rows, XOR-8 swizzle
  __shared__ u16 Vs[2][128 * 32];   // [d][kv] 64B rows, linear
  __shared__ u16 Ps[4][32 * 32];    // per-wave [q][kv] 64B rows, linear

  int tid = threadIdx.x;
  int wv = tid >> 6, lane = tid & 63, lr = lane & 15, lq = lane >> 4;

  // block -> (h, bq, chunk c)
  int id = blockIdx.x;
  int h = id / CPH;
  int w = id - h * CPH;
  int bq = 0, acc = 0;
  for (;;) {
    int ch = (bq + 4) >> 2;
    if (w < acc + ch) break;
    acc += ch;
    ++bq;
  }
  int c = w - acc;
  int nt = 4 * bq + 4;
  int j0 = c * CHT, j1 = min(j0 + CHT, nt);
  int q0 = bq * 128, wrow0 = q0 + wv * 32;

  // Q fragments (pre-scaled): rows wrow0 + mi*16 + lr, k = kd*32 + lq*8
  bf16x8 qf[2][4];
#pragma unroll
  for (int mi = 0; mi < 2; ++mi)
#pragma unroll
    for (int kd = 0; kd < 4; ++kd)
      qf[mi][kd] = *(const bf16x8*)
          &Qh[((size_t)h * T_SEQ + wrow0 + mi * 16 + lr) * HD + kd * 32 + lq * 8];

  f32x4 acc_o[2][8] = {};
  float m_run[2][4], l_run[2][4];
#pragma unroll
  for (int mi = 0; mi < 2; ++mi)
#pragma unroll
    for (int r = 0; r < 4; ++r) { m_run[mi][r] = -1e30f; l_run[mi][r] = 0.0f; }

  auto stage = [&](int buf, int jb) {
#pragma unroll
    for (int k = 0; k < 2; ++k) {      // K tile: 512 chunks, 16/row, src pre-swz
      int cc = k * 256 + tid;
      int row = cc >> 4;
      int sc = (cc ^ (row & 7)) & 15;
      async16(&Kh[((size_t)h * T_SEQ + jb + row) * HD + sc * 8], &Ks[buf][cc * 8]);
    }
#pragma unroll
    for (int k = 0; k < 2; ++k) {      // V tile: 512 chunks, 4/row, linear
      int cc = k * 256 + tid;
      int row = cc >> 2, col = cc & 3;
      async16(&Vt[((size_t)h * HD + row) * T_SEQ + jb + col * 8], &Vs[buf][cc * 8]);
    }
  };

  stage(0, j0 * KVB);
  __syncthreads();

  for (int j = j0; j < j1; ++j) {
    int cur = (j - j0) & 1;
    int jb = j * KVB;
    if (j + 1 < j1) stage(cur ^ 1, jb + KVB);

    if (jb <= wrow0 + 31) {
      const char* KsB = (const char*)&Ks[cur][0];

      // ---- S = Q K^T  (32 x 32) ----
      f32x4 s_acc[2][2] = {};
#pragma unroll
      for (int kd = 0; kd < 4; ++kd) {
#pragma unroll
        for (int nj = 0; nj < 2; ++nj) {
          int row = nj * 16 + lr;
          int byt = (row << 8) + kd * 64 + lq * 16;
          bf16x8 kf = *(const bf16x8*)(KsB + (byt ^ ((row & 7) << 4)));
#pragma unroll
          for (int mi = 0; mi < 2; ++mi)
            s_acc[mi][nj] = __builtin_amdgcn_mfma_f32_16x16x32_bf16(
                qf[mi][kd], kf, s_acc[mi][nj], 0, 0, 0);
        }
      }

      bool diag = (jb + KVB - 1 > wrow0);
      // ---- online softmax (R4 pattern) ----
#pragma unroll
      for (int mi = 0; mi < 2; ++mi) {
        float pm[4];
#pragma unroll
        for (int r = 0; r < 4; ++r) {
          int qrow = wrow0 + mi * 16 + lq * 4 + r;
          float mx = -1e30f;
#pragma unroll
          for (int nj = 0; nj < 2; ++nj) {
            float sv = s_acc[mi][nj][r];
            if (diag && (jb + nj * 16 + lr > qrow)) sv = -1e30f;
            s_acc[mi][nj][r] = sv;
            mx = fmaxf(mx, sv);
          }
          pm[r] = mx;
        }
#pragma unroll
        for (int r = 0; r < 4; ++r) {
          pm[r] = fmaxf(pm[r], __shfl_xor(pm[r], 1));
          pm[r] = fmaxf(pm[r], __shfl_xor(pm[r], 2));
          pm[r] = fmaxf(pm[r], __shfl_xor(pm[r], 4));
          pm[r] = fmaxf(pm[r], __shfl_xor(pm[r], 8));
        }
#pragma unroll
        for (int r = 0; r < 4; ++r) {
          float mnew = fmaxf(m_run[mi][r], pm[r]);
          float sf = exp2f(m_run[mi][r] - mnew);
          m_run[mi][r] = mnew;
          int prow = mi * 16 + lq * 4 + r;
          float rs = 0.0f;
#pragma unroll
          for (int nj = 0; nj < 2; ++nj) {
            float p = exp2f(s_acc[mi][nj][r] - mnew);
            rs += p;
            Ps[wv][prow * 32 + nj * 16 + lr] = f2bf(p);
          }
          rs += __shfl_xor(rs, 1);
          rs += __shfl_xor(rs, 2);
          rs += __shfl_xor(rs, 4);
          rs += __shfl_xor(rs, 8);
          l_run[mi][r] = l_run[mi][r] * sf + rs;
#pragma unroll
          for (int nd = 0; nd < 8; ++nd) acc_o[mi][nd][r] *= sf;
        }
      }

      // ---- O += P V  (32 x 128, K=32) ----
#pragma unroll
      for (int mi = 0; mi < 2; ++mi) {
        bf16x8 pa = *(const bf16x8*)&Ps[wv][(mi * 16 + lr) * 32 + lq * 8];
#pragma unroll
        for (int nd = 0; nd < 8; ++nd) {
          bf16x8 vb = *(const bf16x8*)&Vs[cur][(nd * 16 + lr) * 32 + lq * 8];
          acc_o[mi][nd] = __builtin_amdgcn_mfma_f32_16x16x32_bf16(
              pa, vb, acc_o[mi][nd], 0, 0, 0);
        }
      }
    }
    __syncthreads();
  }

  // epilogue: unnormalized bf16 O-partial [chunk][128][128] + per-row (m,l)
  u16* Op = Opart + (size_t)id * 128 * 128;
#pragma unroll
  for (int mi = 0; mi < 2; ++mi)
#pragma unroll
    for (int r = 0; r < 4; ++r) {
      int rowl = wv * 32 + mi * 16 + lq * 4 + r;
#pragma unroll
      for (int nd = 0; nd < 8; ++nd)
        Op[rowl * 128 + nd * 16 + lr] = f2bf(acc_o[mi][nd][r]);
      if (lr == 0)
        ml[(size_t)id * 128 + rowl] = make_float2(m_run[mi][r], l_run[mi][r]);
    }
}

// ---------------- combine: merge chunk partials -> bf16 attn ---------------------
__global__ __launch_bounds__(256)
void attn_combine(const u16* __restrict__ Opart, const float2* __restrict__ ml,
                  u16* __restrict__ attn) {
  int idx = blockIdx.x * 256 + threadIdx.x;       // T*HID/8 threads
  int e8 = idx * 8;
  int qrow = e8 >> 11;
  int col = e8 & (HID - 1);
  int h = col >> 7, coll = col & 127;
  int bq = qrow >> 7, ql = qrow & 127;
  int a = bq >> 2, r = bq & 3;
  int base = h * CPH + (a + 1) * (2 * a + r);
  int n = (bq + 4) >> 2;

  float m = -1e30f;
  for (int c = 0; c < n; ++c) m = fmaxf(m, ml[(size_t)(base + c) * 128 + ql].x);
  float lsum = 0.0f;
  float o[8] = {};
  for (int c = 0; c < n; ++c) {
    float2 mlc = ml[(size_t)(base + c) * 128 + ql];
    float wgt = exp2f(mlc.x - m);
    lsum += mlc.y * wgt;
    const u16* src = Opart + ((size_t)(base + c) * 128 + ql) * 128 + coll;
    ushort4 v0 = *(const ushort4*)src;
    ushort4 v1 = *(const ushort4*)(src + 4);
    o[0] += bf2f(v0.x) * wgt; o[1] += bf2f(v0.y) * wgt;
    o[2] += bf2f(v0.z) * wgt; o[3] += bf2f(v0.w) * wgt;
    o[4] += bf2f(v1.x) * wgt; o[5] += bf2f(v1.y) * wgt;
    o[6] += bf2f(v1.z) * wgt; o[7] += bf2f(v1.w) * wgt;
  }
  float rl = 1.0f / lsum;
  uint4 w;
  w.x = (u32)f2bf(o[0] * rl) | ((u32)f2bf(o[1] * rl) << 16);
  w.y = (u32)f2bf(o[2] * rl) | ((u32)f2bf(o[3] * rl) << 16);
  w.z = (u32)f2bf(o[4] * rl) | ((u32)f2bf(o[5] * rl) << 16);
  w.w = (u32)f2bf(o[6] * rl) | ((u32)f2bf(o[7] * rl) << 16);
  *(uint4*)&attn[e8] = w;
}

extern "C" void kernel_launch(void* const* d_in, const int* in_sizes, int n_in,
                              void* d_out, int out_size, void* d_ws, size_t ws_size,
                              hipStream_t stream) {
  const float* hidden    = (const float*)d_in[0];
  const int*   positions = (const int*)d_in[1];
  const float* w_qkv     = (const float*)d_in[2];
  const float* w_o       = (const float*)d_in[3];
  float* out = (float*)d_out;

  char* p = (char*)d_ws;
  u16* woT    = (u16*)p;  p += (size_t)HID * HID * 2;
  u16* Qh     = (u16*)p;  p += (size_t)T_SEQ * HID * 2;
  u16* Kh     = (u16*)p;  p += (size_t)T_SEQ * HID * 2;
  u16* Vt     = (u16*)p;  p += (size_t)T_SEQ * HID * 2;
  u16* attn_b = (u16*)p;  p += (size_t)T_SEQ * HID * 2;
  // union region: {hs_b, wqkvT, qkvb} (dead after vtrans) overlaps {Opart, ml}
  // (written by attn_fwd, strictly later in stream order).
  char* un = p;
  u16* hs_b   = (u16*)un;
  u16* wqkvT  = (u16*)(un + (size_t)T_SEQ * HID * 2);
  u16* qkvb   = (u16*)(un + (size_t)T_SEQ * HID * 2 + (size_t)QKVN * HID * 2);
  u16* Opart  = (u16*)un;
  float2* ml  = (float2*)(un + (size_t)NH * CPH * 128 * 128 * 2);

  cast_f32_bf16<<<(T_SEQ * HID / 4 + 255) / 256, 256, 0, stream>>>(hidden, hs_b, T_SEQ * HID);
  transpose_cast<<<dim3(QKVN / 64, HID / 64), 256, 0, stream>>>(w_qkv, wqkvT, HID, QKVN);
  transpose_cast<<<dim3(HID / 64, HID / 64), 256, 0, stream>>>(w_o, woT, HID, HID);
  gemm_bf16_bt<u16><<<dim3(QKVN / 128, T_SEQ / 128), 256, 0, stream>>>(hs_b, wqkvT, qkvb,
                                                                       T_SEQ, QKVN, HID);
  rope_reorg<<<(T_SEQ * NH * 64 + 255) / 256, 256, 0, stream>>>(qkvb, positions, Qh, Kh);
  vtrans<<<dim3(T_SEQ / 64, NH), 256, 0, stream>>>(qkvb, Vt);
  attn_fwd<<<NH * CPH, 256, 0, stream>>>(Qh, Kh, Vt, Opart, ml);
  attn_combine<<<T_SEQ * HID / 8 / 256, 256, 0, stream>>>(Opart, ml, attn_b);
  gemm_bf16_bt<float><<<dim3(HID / 128, T_SEQ / 128), 256, 0, stream>>>(attn_b, woT, out,
                                                                        T_SEQ, HID, HID);
}

// Round 13
// 456.920 us; speedup vs baseline: 1.3805x; 1.0899x over previous
//
#include <hip/hip_runtime.h>
#include <hip/hip_bf16.h>
#include <cstdint>
#include <cstddef>

#define T_SEQ 4096
#define HID   2048
#define NH    16
#define HD    128
#define QKVN  6144
#define KVB   32
#define CHT   16          // KV tiles per chunk
#define CPH   144         // chunks per head

typedef unsigned short u16;
typedef unsigned int u32;
typedef __bf16 bf16x8 __attribute__((ext_vector_type(8)));
typedef float  f32x4  __attribute__((ext_vector_type(4)));

typedef const __attribute__((address_space(1))) void* gas_ptr;
typedef __attribute__((address_space(3))) void* las_ptr;

__device__ __forceinline__ void async16(const void* g, void* l) {
  __builtin_amdgcn_global_load_lds((gas_ptr)g, (las_ptr)l, 16, 0, 0);
}

__device__ __forceinline__ u16 f2bf(float f) {
  unsigned int u = __float_as_uint(f);
  u += 0x7fffu + ((u >> 16) & 1u);
  return (u16)(u >> 16);
}

__device__ __forceinline__ float bf2f(u16 x) {
  return __uint_as_float((unsigned)x << 16);
}

// ---------------- elementwise cast f32 -> bf16 ----------------
__global__ void cast_f32_bf16(const float* __restrict__ in, u16* __restrict__ out, int n) {
  int i = (blockIdx.x * blockDim.x + threadIdx.x) * 4;
  if (i >= n) return;
  float4 v = *(const float4*)&in[i];
  uint2 o;
  o.x = (unsigned)f2bf(v.x) | ((unsigned)f2bf(v.y) << 16);
  o.y = (unsigned)f2bf(v.z) | ((unsigned)f2bf(v.w) << 16);
  *(uint2*)&out[i] = o;
}

// ---------------- transpose + cast: f32 [R][C] -> bf16 [C][R] ----------------
__global__ void transpose_cast(const float* __restrict__ in, u16* __restrict__ out,
                               int R, int C) {
  __shared__ float tile[64][65];
  int c0 = blockIdx.x * 64, r0 = blockIdx.y * 64;
  int tid = threadIdx.x;
#pragma unroll
  for (int i = 0; i < 16; ++i) {
    int e = i * 256 + tid;
    int rr = e >> 6, cc = e & 63;
    tile[rr][cc] = in[(size_t)(r0 + rr) * C + c0 + cc];
  }
  __syncthreads();
#pragma unroll
  for (int i = 0; i < 16; ++i) {
    int e = i * 256 + tid;
    int oc = e >> 6, orr = e & 63;
    out[(size_t)(c0 + oc) * R + r0 + orr] = f2bf(tile[orr][oc]);
  }
}

// ---------------- GEMM: C[M][N] = A[M][K] * BT[N][K]^T  (bf16 in) ----------------
// 128x128 tile, BK=32, plain dbuf; key-swizzled LDS.
template <typename OUT>
__global__ __launch_bounds__(256)
void gemm_bf16_bt(const u16* __restrict__ A, const u16* __restrict__ BT,
                  OUT* __restrict__ C, int M, int N, int K) {
  __shared__ u16 As[2][128 * 32];
  __shared__ u16 Bs[2][128 * 32];
  int tid = threadIdx.x;
  int row0 = blockIdx.y * 128, col0 = blockIdx.x * 128;
  int wv = tid >> 6, lane = tid & 63, lr = lane & 15, lq = lane >> 4;
  int wm = (wv >> 1) * 64, wn = (wv & 1) * 64;
  f32x4 acc[4][4] = {};

  auto stage = [&](int buf, int ks) {
#pragma unroll
    for (int k = 0; k < 2; ++k) {
      int c = k * 256 + tid;            // 512 chunks/matrix; dest lane-linear
      int row = c >> 2, col = c & 3;
      int key = (row >> 1) & 3;
      async16(&A[(size_t)(row0 + row) * K + ks + (col ^ key) * 8], &As[buf][c * 8]);
      async16(&BT[(size_t)(col0 + row) * K + ks + (col ^ key) * 8], &Bs[buf][c * 8]);
    }
  };

  stage(0, 0);
  __syncthreads();
  int nk = K >> 5;
  for (int t = 0; t < nk; ++t) {
    int cur = t & 1;
    if (t + 1 < nk) stage(cur ^ 1, (t + 1) * 32);

    const char* AsB = (const char*)&As[cur][0];
    const char* BsB = (const char*)&Bs[cur][0];
    bf16x8 a[4], b[4];
#pragma unroll
    for (int mi = 0; mi < 4; ++mi) {
      int row = wm + mi * 16 + lr;
      a[mi] = *(const bf16x8*)(AsB + row * 64 + ((lq ^ ((row >> 1) & 3)) << 4));
    }
#pragma unroll
    for (int ni = 0; ni < 4; ++ni) {
      int row = wn + ni * 16 + lr;
      b[ni] = *(const bf16x8*)(BsB + row * 64 + ((lq ^ ((row >> 1) & 3)) << 4));
    }
#pragma unroll
    for (int mi = 0; mi < 4; ++mi)
#pragma unroll
      for (int ni = 0; ni < 4; ++ni)
        acc[mi][ni] = __builtin_amdgcn_mfma_f32_16x16x32_bf16(a[mi], b[ni], acc[mi][ni], 0, 0, 0);
    __syncthreads();
  }

#pragma unroll
  for (int mi = 0; mi < 4; ++mi)
#pragma unroll
    for (int ni = 0; ni < 4; ++ni)
#pragma unroll
      for (int r = 0; r < 4; ++r) {
        float v = acc[mi][ni][r];
        size_t idx = (size_t)(row0 + wm + mi * 16 + lq * 4 + r) * N + col0 + wn + ni * 16 + lr;
        if constexpr (sizeof(OUT) == 2) C[idx] = (OUT)f2bf(v);
        else                            C[idx] = (OUT)v;
      }
}

// ---------------- RoPE + head-major reorg for Q,K (bf16 qkv input) ----------------
// Q pre-scaled by (1/sqrt(HD)) * log2(e) so softmax uses exp2 directly.
#define SCL2 0.12753224f

__global__ void rope_reorg(const u16* __restrict__ qkv, const int* __restrict__ pos,
                           u16* __restrict__ Qh, u16* __restrict__ Kh) {
  int idx = blockIdx.x * 256 + threadIdx.x;
  if (idx >= T_SEQ * NH * 64) return;
  int d = idx & 63;
  int h = (idx >> 6) & (NH - 1);
  int t = idx >> 10;
  float p = (float)pos[t];
  float inv = exp2f((float)d * -0.20762050594046932f);
  float f = p * inv;
  float s, c;
  __sincosf(f, &s, &c);

  size_t ib = (size_t)t * QKVN + h * HD + d;
  float q1 = bf2f(qkv[ib]), q2 = bf2f(qkv[ib + 64]);
  float k1 = bf2f(qkv[ib + HID]), k2 = bf2f(qkv[ib + HID + 64]);
  size_t ob = ((size_t)h * T_SEQ + t) * HD + d;
  Qh[ob]      = f2bf((q1 * c - q2 * s) * SCL2);
  Qh[ob + 64] = f2bf((q2 * c + q1 * s) * SCL2);
  Kh[ob]      = f2bf(k1 * c - k2 * s);
  Kh[ob + 64] = f2bf(k2 * c + k1 * s);
}

// ---------------- V transpose: qkv v-part bf16 -> Vt bf16 [NH][HD][T] -------------
__global__ void vtrans(const u16* __restrict__ qkv, u16* __restrict__ Vt) {
  __shared__ u16 tile[64][136];   // +8 u16 pad
  int t0 = blockIdx.x * 64;
  int h = blockIdx.y;
  int tid = threadIdx.x;
#pragma unroll
  for (int i = 0; i < 32; ++i) {
    int e = i * 256 + tid;
    int tt = e >> 7, d = e & 127;
    tile[tt][d] = qkv[(size_t)(t0 + tt) * QKVN + 2 * HID + h * HD + d];
  }
  __syncthreads();
#pragma unroll
  for (int i = 0; i < 32; ++i) {
    int e = i * 256 + tid;
    int d = e >> 6, tt = e & 63;
    Vt[((size_t)h * HD + d) * T_SEQ + t0 + tt] = tile[tt][d];
  }
}

// ---------------- causal flash attention v13: R12 body + throughput cuts ---------
// 2304 uniform chunks (R12 grid). Changes vs R12, each independently proven:
//  (a) defer l-sum: per-lane partial l (exact; sf row-uniform), epilogue reduce
//      -> -32 shfl/tile.   (R5)
//  (b) V key-swizzle (row>>1)&3 on stage source + PV read.   (R9)
//  (c) P XOR-swizzle byte^=(prow&3)<<4 within 64B rows (bijective, 16B-block
//      preserving) -> conflict-free-ish without the LDS-size cost of padding.
__global__ __launch_bounds__(256)
void attn_fwd(const u16* __restrict__ Qh, const u16* __restrict__ Kh,
              const u16* __restrict__ Vt, u16* __restrict__ Opart,
              float2* __restrict__ ml) {
  __shared__ u16 Ks[2][32 * 128];   // [kv][d] 256B rows, XOR-8 swizzle
  __shared__ u16 Vs[2][128 * 32];   // [d][kv] 64B rows, key=(row>>1)&3
  __shared__ u16 Ps[4][32 * 32];    // per-wave [q][kv] 64B rows, XOR-4 swizzle

  int tid = threadIdx.x;
  int wv = tid >> 6, lane = tid & 63, lr = lane & 15, lq = lane >> 4;
  char* PsB = (char*)&Ps[wv][0];

  // block -> (h, bq, chunk c)
  int id = blockIdx.x;
  int h = id / CPH;
  int w = id - h * CPH;
  int bq = 0, acc = 0;
  for (;;) {
    int ch = (bq + 4) >> 2;
    if (w < acc + ch) break;
    acc += ch;
    ++bq;
  }
  int c = w - acc;
  int nt = 4 * bq + 4;
  int j0 = c * CHT, j1 = min(j0 + CHT, nt);
  int q0 = bq * 128, wrow0 = q0 + wv * 32;

  // Q fragments (pre-scaled): rows wrow0 + mi*16 + lr, k = kd*32 + lq*8
  bf16x8 qf[2][4];
#pragma unroll
  for (int mi = 0; mi < 2; ++mi)
#pragma unroll
    for (int kd = 0; kd < 4; ++kd)
      qf[mi][kd] = *(const bf16x8*)
          &Qh[((size_t)h * T_SEQ + wrow0 + mi * 16 + lr) * HD + kd * 32 + lq * 8];

  f32x4 acc_o[2][8] = {};
  float m_run[2][4], l_run[2][4];
#pragma unroll
  for (int mi = 0; mi < 2; ++mi)
#pragma unroll
    for (int r = 0; r < 4; ++r) { m_run[mi][r] = -1e30f; l_run[mi][r] = 0.0f; }

  auto stage = [&](int buf, int jb) {
#pragma unroll
    for (int k = 0; k < 2; ++k) {      // K tile: 512 chunks, 16/row, src pre-swz
      int cc = k * 256 + tid;
      int row = cc >> 4;
      int sc = (cc ^ (row & 7)) & 15;
      async16(&Kh[((size_t)h * T_SEQ + jb + row) * HD + sc * 8], &Ks[buf][cc * 8]);
    }
#pragma unroll
    for (int k = 0; k < 2; ++k) {      // V tile: 512 chunks, 4/row, key-swz
      int cc = k * 256 + tid;
      int row = cc >> 2, col = cc & 3;
      int key = (row >> 1) & 3;
      async16(&Vt[((size_t)h * HD + row) * T_SEQ + jb + (col ^ key) * 8],
              &Vs[buf][cc * 8]);
    }
  };

  stage(0, j0 * KVB);
  __syncthreads();

  for (int j = j0; j < j1; ++j) {
    int cur = (j - j0) & 1;
    int jb = j * KVB;
    if (j + 1 < j1) stage(cur ^ 1, jb + KVB);

    if (jb <= wrow0 + 31) {
      const char* KsB = (const char*)&Ks[cur][0];
      const char* VsB = (const char*)&Vs[cur][0];

      // ---- S = Q K^T  (32 x 32) ----
      f32x4 s_acc[2][2] = {};
#pragma unroll
      for (int kd = 0; kd < 4; ++kd) {
#pragma unroll
        for (int nj = 0; nj < 2; ++nj) {
          int row = nj * 16 + lr;
          int byt = (row << 8) + kd * 64 + lq * 16;
          bf16x8 kf = *(const bf16x8*)(KsB + (byt ^ ((row & 7) << 4)));
#pragma unroll
          for (int mi = 0; mi < 2; ++mi)
            s_acc[mi][nj] = __builtin_amdgcn_mfma_f32_16x16x32_bf16(
                qf[mi][kd], kf, s_acc[mi][nj], 0, 0, 0);
        }
      }

      bool diag = (jb + KVB - 1 > wrow0);
      // ---- online softmax (per-lane partial l; 4-shfl max reduce only) ----
#pragma unroll
      for (int mi = 0; mi < 2; ++mi) {
        float pm[4];
#pragma unroll
        for (int r = 0; r < 4; ++r) {
          int qrow = wrow0 + mi * 16 + lq * 4 + r;
          float mx = -1e30f;
#pragma unroll
          for (int nj = 0; nj < 2; ++nj) {
            float sv = s_acc[mi][nj][r];
            if (diag && (jb + nj * 16 + lr > qrow)) sv = -1e30f;
            s_acc[mi][nj][r] = sv;
            mx = fmaxf(mx, sv);
          }
          pm[r] = mx;
        }
#pragma unroll
        for (int r = 0; r < 4; ++r) {
          pm[r] = fmaxf(pm[r], __shfl_xor(pm[r], 1));
          pm[r] = fmaxf(pm[r], __shfl_xor(pm[r], 2));
          pm[r] = fmaxf(pm[r], __shfl_xor(pm[r], 4));
          pm[r] = fmaxf(pm[r], __shfl_xor(pm[r], 8));
        }
#pragma unroll
        for (int r = 0; r < 4; ++r) {
          float mnew = fmaxf(m_run[mi][r], pm[r]);
          float sf = exp2f(m_run[mi][r] - mnew);
          m_run[mi][r] = mnew;
          int prow = mi * 16 + lq * 4 + r;
          float rs = 0.0f;
#pragma unroll
          for (int nj = 0; nj < 2; ++nj) {
            float p = exp2f(s_acc[mi][nj][r] - mnew);
            rs += p;
            *(u16*)(PsB + prow * 64 + (((nj * 16 + lr) * 2) ^ ((prow & 3) << 4))) = f2bf(p);
          }
          l_run[mi][r] = l_run[mi][r] * sf + rs;   // per-lane partial
#pragma unroll
          for (int nd = 0; nd < 8; ++nd) acc_o[mi][nd][r] *= sf;
        }
      }

      // ---- O += P V  (32 x 128, K=32) ----
#pragma unroll
      for (int mi = 0; mi < 2; ++mi) {
        int prow = mi * 16 + lr;
        bf16x8 pa = *(const bf16x8*)(PsB + prow * 64 + ((lq ^ (prow & 3)) << 4));
#pragma unroll
        for (int nd = 0; nd < 8; ++nd) {
          int vrow = nd * 16 + lr;
          bf16x8 vb = *(const bf16x8*)(VsB + vrow * 64 + ((lq ^ ((vrow >> 1) & 3)) << 4));
          acc_o[mi][nd] = __builtin_amdgcn_mfma_f32_16x16x32_bf16(
              pa, vb, acc_o[mi][nd], 0, 0, 0);
        }
      }
    }
    __syncthreads();
  }

  // epilogue: reduce per-lane partial l; unnormalized bf16 O-partial + (m,l)
  u16* Op = Opart + (size_t)id * 128 * 128;
#pragma unroll
  for (int mi = 0; mi < 2; ++mi)
#pragma unroll
    for (int r = 0; r < 4; ++r) {
      float l = l_run[mi][r];
      l += __shfl_xor(l, 1);
      l += __shfl_xor(l, 2);
      l += __shfl_xor(l, 4);
      l += __shfl_xor(l, 8);
      int rowl = wv * 32 + mi * 16 + lq * 4 + r;
#pragma unroll
      for (int nd = 0; nd < 8; ++nd)
        Op[rowl * 128 + nd * 16 + lr] = f2bf(acc_o[mi][nd][r]);
      if (lr == 0)
        ml[(size_t)id * 128 + rowl] = make_float2(m_run[mi][r], l);
    }
}

// ---------------- combine: merge chunk partials -> bf16 attn ---------------------
__global__ __launch_bounds__(256)
void attn_combine(const u16* __restrict__ Opart, const float2* __restrict__ ml,
                  u16* __restrict__ attn) {
  int idx = blockIdx.x * 256 + threadIdx.x;       // T*HID/8 threads
  int e8 = idx * 8;
  int qrow = e8 >> 11;
  int col = e8 & (HID - 1);
  int h = col >> 7, coll = col & 127;
  int bq = qrow >> 7, ql = qrow & 127;
  int a = bq >> 2, r = bq & 3;
  int base = h * CPH + (a + 1) * (2 * a + r);
  int n = (bq + 4) >> 2;

  float m = -1e30f;
  for (int c = 0; c < n; ++c) m = fmaxf(m, ml[(size_t)(base + c) * 128 + ql].x);
  float lsum = 0.0f;
  float o[8] = {};
  for (int c = 0; c < n; ++c) {
    float2 mlc = ml[(size_t)(base + c) * 128 + ql];
    float wgt = exp2f(mlc.x - m);
    lsum += mlc.y * wgt;
    const u16* src = Opart + ((size_t)(base + c) * 128 + ql) * 128 + coll;
    ushort4 v0 = *(const ushort4*)src;
    ushort4 v1 = *(const ushort4*)(src + 4);
    o[0] += bf2f(v0.x) * wgt; o[1] += bf2f(v0.y) * wgt;
    o[2] += bf2f(v0.z) * wgt; o[3] += bf2f(v0.w) * wgt;
    o[4] += bf2f(v1.x) * wgt; o[5] += bf2f(v1.y) * wgt;
    o[6] += bf2f(v1.z) * wgt; o[7] += bf2f(v1.w) * wgt;
  }
  float rl = 1.0f / lsum;
  uint4 w;
  w.x = (u32)f2bf(o[0] * rl) | ((u32)f2bf(o[1] * rl) << 16);
  w.y = (u32)f2bf(o[2] * rl) | ((u32)f2bf(o[3] * rl) << 16);
  w.z = (u32)f2bf(o[4] * rl) | ((u32)f2bf(o[5] * rl) << 16);
  w.w = (u32)f2bf(o[6] * rl) | ((u32)f2bf(o[7] * rl) << 16);
  *(uint4*)&attn[e8] = w;
}

extern "C" void kernel_launch(void* const* d_in, const int* in_sizes, int n_in,
                              void* d_out, int out_size, void* d_ws, size_t ws_size,
                              hipStream_t stream) {
  const float* hidden    = (const float*)d_in[0];
  const int*   positions = (const int*)d_in[1];
  const float* w_qkv     = (const float*)d_in[2];
  const float* w_o       = (const float*)d_in[3];
  float* out = (float*)d_out;

  char* p = (char*)d_ws;
  u16* woT    = (u16*)p;  p += (size_t)HID * HID * 2;
  u16* Qh     = (u16*)p;  p += (size_t)T_SEQ * HID * 2;
  u16* Kh     = (u16*)p;  p += (size_t)T_SEQ * HID * 2;
  u16* Vt     = (u16*)p;  p += (size_t)T_SEQ * HID * 2;
  u16* attn_b = (u16*)p;  p += (size_t)T_SEQ * HID * 2;
  // union region: {hs_b, wqkvT, qkvb} (dead after vtrans) overlaps {Opart, ml}
  // (written by attn_fwd, strictly later in stream order).
  char* un = p;
  u16* hs_b   = (u16*)un;
  u16* wqkvT  = (u16*)(un + (size_t)T_SEQ * HID * 2);
  u16* qkvb   = (u16*)(un + (size_t)T_SEQ * HID * 2 + (size_t)QKVN * HID * 2);
  u16* Opart  = (u16*)un;
  float2* ml  = (float2*)(un + (size_t)NH * CPH * 128 * 128 * 2);

  cast_f32_bf16<<<(T_SEQ * HID / 4 + 255) / 256, 256, 0, stream>>>(hidden, hs_b, T_SEQ * HID);
  transpose_cast<<<dim3(QKVN / 64, HID / 64), 256, 0, stream>>>(w_qkv, wqkvT, HID, QKVN);
  transpose_cast<<<dim3(HID / 64, HID / 64), 256, 0, stream>>>(w_o, woT, HID, HID);
  gemm_bf16_bt<u16><<<dim3(QKVN / 128, T_SEQ / 128), 256, 0, stream>>>(hs_b, wqkvT, qkvb,
                                                                       T_SEQ, QKVN, HID);
  rope_reorg<<<(T_SEQ * NH * 64 + 255) / 256, 256, 0, stream>>>(qkvb, positions, Qh, Kh);
  vtrans<<<dim3(T_SEQ / 64, NH), 256, 0, stream>>>(qkvb, Vt);
  attn_fwd<<<NH * CPH, 256, 0, stream>>>(Qh, Kh, Vt, Opart, ml);
  attn_combine<<<T_SEQ * HID / 8 / 256, 256, 0, stream>>>(Opart, ml, attn_b);
  gemm_bf16_bt<float><<<dim3(HID / 128, T_SEQ / 128), 256, 0, stream>>>(attn_b, woT, out,
                                                                        T_SEQ, HID, HID);
}

// Round 14
// 416.322 us; speedup vs baseline: 1.5151x; 1.0975x over previous
//
#include <hip/hip_runtime.h>
#include <hip/hip_bf16.h>
#include <cstdint>
#include <cstddef>

#define T_SEQ 4096
#define HID   2048
#define NH    16
#define HD    128
#define QKVN  6144
#define KVB   32
#define CHT   16          // KV tiles per chunk
#define CPH   144         // chunks per head

typedef unsigned short u16;
typedef unsigned int u32;
typedef __bf16 bf16x8 __attribute__((ext_vector_type(8)));
typedef float  f32x4  __attribute__((ext_vector_type(4)));

typedef const __attribute__((address_space(1))) void* gas_ptr;
typedef __attribute__((address_space(3))) void* las_ptr;

__device__ __forceinline__ void async16(const void* g, void* l) {
  __builtin_amdgcn_global_load_lds((gas_ptr)g, (las_ptr)l, 16, 0, 0);
}

__device__ __forceinline__ u16 f2bf(float f) {
  unsigned int u = __float_as_uint(f);
  u += 0x7fffu + ((u >> 16) & 1u);
  return (u16)(u >> 16);
}

__device__ __forceinline__ float bf2f(u16 x) {
  return __uint_as_float((unsigned)x << 16);
}

// ---------------- elementwise cast f32 -> bf16 ----------------
__global__ void cast_f32_bf16(const float* __restrict__ in, u16* __restrict__ out, int n) {
  int i = (blockIdx.x * blockDim.x + threadIdx.x) * 4;
  if (i >= n) return;
  float4 v = *(const float4*)&in[i];
  uint2 o;
  o.x = (unsigned)f2bf(v.x) | ((unsigned)f2bf(v.y) << 16);
  o.y = (unsigned)f2bf(v.z) | ((unsigned)f2bf(v.w) << 16);
  *(uint2*)&out[i] = o;
}

// ---------------- transpose + cast: f32 [R][C] -> bf16 [C][R] ----------------
__global__ void transpose_cast(const float* __restrict__ in, u16* __restrict__ out,
                               int R, int C) {
  __shared__ float tile[64][65];
  int c0 = blockIdx.x * 64, r0 = blockIdx.y * 64;
  int tid = threadIdx.x;
#pragma unroll
  for (int i = 0; i < 16; ++i) {
    int e = i * 256 + tid;
    int rr = e >> 6, cc = e & 63;
    tile[rr][cc] = in[(size_t)(r0 + rr) * C + c0 + cc];
  }
  __syncthreads();
#pragma unroll
  for (int i = 0; i < 16; ++i) {
    int e = i * 256 + tid;
    int oc = e >> 6, orr = e & 63;
    out[(size_t)(c0 + oc) * R + r0 + orr] = f2bf(tile[orr][oc]);
  }
}

// ---------------- GEMM: C[M][N] = A[M][K] * BT[N][K]^T  (bf16 in) ----------------
// 128x128 tile, BK=32, plain dbuf; key-swizzled LDS.
template <typename OUT>
__global__ __launch_bounds__(256)
void gemm_bf16_bt(const u16* __restrict__ A, const u16* __restrict__ BT,
                  OUT* __restrict__ C, int M, int N, int K) {
  __shared__ u16 As[2][128 * 32];
  __shared__ u16 Bs[2][128 * 32];
  int tid = threadIdx.x;
  int row0 = blockIdx.y * 128, col0 = blockIdx.x * 128;
  int wv = tid >> 6, lane = tid & 63, lr = lane & 15, lq = lane >> 4;
  int wm = (wv >> 1) * 64, wn = (wv & 1) * 64;
  f32x4 acc[4][4] = {};

  auto stage = [&](int buf, int ks) {
#pragma unroll
    for (int k = 0; k < 2; ++k) {
      int c = k * 256 + tid;            // 512 chunks/matrix; dest lane-linear
      int row = c >> 2, col = c & 3;
      int key = (row >> 1) & 3;
      async16(&A[(size_t)(row0 + row) * K + ks + (col ^ key) * 8], &As[buf][c * 8]);
      async16(&BT[(size_t)(col0 + row) * K + ks + (col ^ key) * 8], &Bs[buf][c * 8]);
    }
  };

  stage(0, 0);
  __syncthreads();
  int nk = K >> 5;
  for (int t = 0; t < nk; ++t) {
    int cur = t & 1;
    if (t + 1 < nk) stage(cur ^ 1, (t + 1) * 32);

    const char* AsB = (const char*)&As[cur][0];
    const char* BsB = (const char*)&Bs[cur][0];
    bf16x8 a[4], b[4];
#pragma unroll
    for (int mi = 0; mi < 4; ++mi) {
      int row = wm + mi * 16 + lr;
      a[mi] = *(const bf16x8*)(AsB + row * 64 + ((lq ^ ((row >> 1) & 3)) << 4));
    }
#pragma unroll
    for (int ni = 0; ni < 4; ++ni) {
      int row = wn + ni * 16 + lr;
      b[ni] = *(const bf16x8*)(BsB + row * 64 + ((lq ^ ((row >> 1) & 3)) << 4));
    }
#pragma unroll
    for (int mi = 0; mi < 4; ++mi)
#pragma unroll
      for (int ni = 0; ni < 4; ++ni)
        acc[mi][ni] = __builtin_amdgcn_mfma_f32_16x16x32_bf16(a[mi], b[ni], acc[mi][ni], 0, 0, 0);
    __syncthreads();
  }

#pragma unroll
  for (int mi = 0; mi < 4; ++mi)
#pragma unroll
    for (int ni = 0; ni < 4; ++ni)
#pragma unroll
      for (int r = 0; r < 4; ++r) {
        float v = acc[mi][ni][r];
        size_t idx = (size_t)(row0 + wm + mi * 16 + lq * 4 + r) * N + col0 + wn + ni * 16 + lr;
        if constexpr (sizeof(OUT) == 2) C[idx] = (OUT)f2bf(v);
        else                            C[idx] = (OUT)v;
      }
}

// ---------------- RoPE + head-major reorg for Q,K (bf16 qkv input) ----------------
// Q pre-scaled by (1/sqrt(HD)) * log2(e) so softmax uses exp2 directly.
#define SCL2 0.12753224f

__global__ void rope_reorg(const u16* __restrict__ qkv, const int* __restrict__ pos,
                           u16* __restrict__ Qh, u16* __restrict__ Kh) {
  int idx = blockIdx.x * 256 + threadIdx.x;
  if (idx >= T_SEQ * NH * 64) return;
  int d = idx & 63;
  int h = (idx >> 6) & (NH - 1);
  int t = idx >> 10;
  float p = (float)pos[t];
  float inv = exp2f((float)d * -0.20762050594046932f);
  float f = p * inv;
  float s, c;
  __sincosf(f, &s, &c);

  size_t ib = (size_t)t * QKVN + h * HD + d;
  float q1 = bf2f(qkv[ib]), q2 = bf2f(qkv[ib + 64]);
  float k1 = bf2f(qkv[ib + HID]), k2 = bf2f(qkv[ib + HID + 64]);
  size_t ob = ((size_t)h * T_SEQ + t) * HD + d;
  Qh[ob]      = f2bf((q1 * c - q2 * s) * SCL2);
  Qh[ob + 64] = f2bf((q2 * c + q1 * s) * SCL2);
  Kh[ob]      = f2bf(k1 * c - k2 * s);
  Kh[ob + 64] = f2bf(k2 * c + k1 * s);
}

// ---------------- V transpose: qkv v-part bf16 -> Vt bf16 [NH][HD][T] -------------
__global__ void vtrans(const u16* __restrict__ qkv, u16* __restrict__ Vt) {
  __shared__ u16 tile[64][136];   // +8 u16 pad
  int t0 = blockIdx.x * 64;
  int h = blockIdx.y;
  int tid = threadIdx.x;
#pragma unroll
  for (int i = 0; i < 32; ++i) {
    int e = i * 256 + tid;
    int tt = e >> 7, d = e & 127;
    tile[tt][d] = qkv[(size_t)(t0 + tt) * QKVN + 2 * HID + h * HD + d];
  }
  __syncthreads();
#pragma unroll
  for (int i = 0; i < 32; ++i) {
    int e = i * 256 + tid;
    int d = e >> 6, tt = e & 63;
    Vt[((size_t)h * HD + d) * T_SEQ + t0 + tt] = tile[tt][d];
  }
}

// ---------------- causal flash attention v14: R13 chunks + swapped-QK^T softmax --
// 2304 uniform chunks (R12/R13 grid). S^T = mfma(K,Q): lane (lq,lr) holds
// S[k=lq*4+r][q=lr] -> in-lane mask, 2-shfl row max, per-lane partial l,
// P packed as 4x uint2 writes. P/V swizzle key = ((row>>1)&3)<<4 (derived
// 2-way = free; R13's (row&3) key was degenerate per-instruction).
__global__ __launch_bounds__(256)
void attn_fwd(const u16* __restrict__ Qh, const u16* __restrict__ Kh,
              const u16* __restrict__ Vt, u16* __restrict__ Opart,
              float2* __restrict__ ml) {
  __shared__ u16 Ks[2][32 * 128];   // [kv][d] 256B rows, XOR-8 swizzle
  __shared__ u16 Vs[2][128 * 32];   // [d][kv] 64B rows, key=(row>>1)&3
  __shared__ u16 Ps[4][32 * 32];    // per-wave [q][kv] 64B rows, key=(row>>1)&3

  int tid = threadIdx.x;
  int wv = tid >> 6, lane = tid & 63, lr = lane & 15, lq = lane >> 4;
  char* PsB = (char*)&Ps[wv][0];

  // block -> (h, bq, chunk c)
  int id = blockIdx.x;
  int h = id / CPH;
  int w = id - h * CPH;
  int bq = 0, acc = 0;
  for (;;) {
    int ch = (bq + 4) >> 2;
    if (w < acc + ch) break;
    acc += ch;
    ++bq;
  }
  int c = w - acc;
  int nt = 4 * bq + 4;
  int j0 = c * CHT, j1 = min(j0 + CHT, nt);
  int q0 = bq * 128, wrow0 = q0 + wv * 32;

  // Q fragments (pre-scaled): rows wrow0 + qi*16 + lr, k = kd*32 + lq*8
  bf16x8 qf[2][4];
#pragma unroll
  for (int qi = 0; qi < 2; ++qi)
#pragma unroll
    for (int kd = 0; kd < 4; ++kd)
      qf[qi][kd] = *(const bf16x8*)
          &Qh[((size_t)h * T_SEQ + wrow0 + qi * 16 + lr) * HD + kd * 32 + lq * 8];

  f32x4 acc_o[2][8] = {};
  float m_run[2] = {-1e30f, -1e30f};
  float l_run[2] = {0.0f, 0.0f};

  auto stage = [&](int buf, int jb) {
#pragma unroll
    for (int k = 0; k < 2; ++k) {      // K tile: 512 chunks, 16/row, src pre-swz
      int cc = k * 256 + tid;
      int row = cc >> 4;
      int sc = (cc ^ (row & 7)) & 15;
      async16(&Kh[((size_t)h * T_SEQ + jb + row) * HD + sc * 8], &Ks[buf][cc * 8]);
    }
#pragma unroll
    for (int k = 0; k < 2; ++k) {      // V tile: 512 chunks, 4/row, key-swz
      int cc = k * 256 + tid;
      int row = cc >> 2, col = cc & 3;
      int key = (row >> 1) & 3;
      async16(&Vt[((size_t)h * HD + row) * T_SEQ + jb + (col ^ key) * 8],
              &Vs[buf][cc * 8]);
    }
  };

  stage(0, j0 * KVB);
  __syncthreads();

  for (int j = j0; j < j1; ++j) {
    int cur = (j - j0) & 1;
    int jb = j * KVB;
    if (j + 1 < j1) stage(cur ^ 1, jb + KVB);

    if (jb <= wrow0 + 31) {
      const char* KsB = (const char*)&Ks[cur][0];
      const char* VsB = (const char*)&Vs[cur][0];

      // ---- S^T = K Q^T (swapped): st[kj][qi][r] = S[k=jb+kj*16+lq*4+r]
      //      [q=wrow0+qi*16+lr] ----
      f32x4 st[2][2] = {};
#pragma unroll
      for (int kd = 0; kd < 4; ++kd) {
#pragma unroll
        for (int kj = 0; kj < 2; ++kj) {
          int row = kj * 16 + lr;
          int byt = (row << 8) + kd * 64 + lq * 16;
          bf16x8 kf = *(const bf16x8*)(KsB + (byt ^ ((row & 7) << 4)));
#pragma unroll
          for (int qi = 0; qi < 2; ++qi)
            st[kj][qi] = __builtin_amdgcn_mfma_f32_16x16x32_bf16(
                kf, qf[qi][kd], st[kj][qi], 0, 0, 0);
        }
      }

      // ---- causal mask (in-lane) ----
      if (jb + KVB - 1 > wrow0) {
#pragma unroll
        for (int qi = 0; qi < 2; ++qi) {
          int qg = wrow0 + qi * 16 + lr;
#pragma unroll
          for (int kj = 0; kj < 2; ++kj)
#pragma unroll
            for (int r = 0; r < 4; ++r)
              if (jb + kj * 16 + lq * 4 + r > qg) st[kj][qi][r] = -1e30f;
        }
      }

      // ---- in-register softmax per q-column ----
      float sf[2];
#pragma unroll
      for (int qi = 0; qi < 2; ++qi) {
        float mx = fmaxf(fmaxf(fmaxf(st[0][qi][0], st[0][qi][1]),
                               fmaxf(st[0][qi][2], st[0][qi][3])),
                         fmaxf(fmaxf(st[1][qi][0], st[1][qi][1]),
                               fmaxf(st[1][qi][2], st[1][qi][3])));
        mx = fmaxf(mx, __shfl_xor(mx, 16));
        mx = fmaxf(mx, __shfl_xor(mx, 32));
        float mnew = fmaxf(m_run[qi], mx);
        sf[qi] = exp2f(m_run[qi] - mnew);
        m_run[qi] = mnew;

        int rowb = (qi * 16 + lr) * 64;
        int key = ((lr >> 1) & 3) << 4;
        float rs = 0.0f;
#pragma unroll
        for (int kj = 0; kj < 2; ++kj) {
          float p0 = exp2f(st[kj][qi][0] - mnew);
          float p1 = exp2f(st[kj][qi][1] - mnew);
          float p2 = exp2f(st[kj][qi][2] - mnew);
          float p3 = exp2f(st[kj][qi][3] - mnew);
          rs += (p0 + p1) + (p2 + p3);
          uint2 wq;
          wq.x = (u32)f2bf(p0) | ((u32)f2bf(p1) << 16);
          wq.y = (u32)f2bf(p2) | ((u32)f2bf(p3) << 16);
          *(uint2*)(PsB + rowb + (((kj * 16 + lq * 4) * 2) ^ key)) = wq;
        }
        l_run[qi] = l_run[qi] * sf[qi] + rs;   // per-lane partial (lq-slice)
      }

      // ---- broadcast rescale factors to acc layout, rescale O ----
#pragma unroll
      for (int mi = 0; mi < 2; ++mi) {
        float sfb[4];
#pragma unroll
        for (int r = 0; r < 4; ++r) sfb[r] = __shfl(sf[mi], lq * 4 + r);
#pragma unroll
        for (int nd = 0; nd < 8; ++nd)
#pragma unroll
          for (int r = 0; r < 4; ++r) acc_o[mi][nd][r] *= sfb[r];
      }

      // ---- O += P V  (32 x 128, K=32) ----
#pragma unroll
      for (int mi = 0; mi < 2; ++mi) {
        int prow = mi * 16 + lr;
        bf16x8 pa = *(const bf16x8*)(PsB + prow * 64 + ((lq ^ ((lr >> 1) & 3)) << 4));
#pragma unroll
        for (int nd = 0; nd < 8; ++nd) {
          int vrow = nd * 16 + lr;
          bf16x8 vb = *(const bf16x8*)(VsB + vrow * 64 + ((lq ^ ((vrow >> 1) & 3)) << 4));
          acc_o[mi][nd] = __builtin_amdgcn_mfma_f32_16x16x32_bf16(
              pa, vb, acc_o[mi][nd], 0, 0, 0);
        }
      }
    }
    __syncthreads();
  }

  // epilogue: reduce per-lane partial l across lq; store unnormalized bf16
  // O-partial + per-row (m,l)
  u16* Op = Opart + (size_t)id * 128 * 128;
#pragma unroll
  for (int mi = 0; mi < 2; ++mi) {
    float l = l_run[mi];
    l += __shfl_xor(l, 16);
    l += __shfl_xor(l, 32);
    if (lq == 0) {
      int rowl = wv * 32 + mi * 16 + lr;
      ml[(size_t)id * 128 + rowl] = make_float2(m_run[mi], l);
    }
#pragma unroll
    for (int r = 0; r < 4; ++r) {
      int rowl = wv * 32 + mi * 16 + lq * 4 + r;
#pragma unroll
      for (int nd = 0; nd < 8; ++nd)
        Op[rowl * 128 + nd * 16 + lr] = f2bf(acc_o[mi][nd][r]);
    }
  }
}

// ---------------- combine: merge chunk partials -> bf16 attn ---------------------
__global__ __launch_bounds__(256)
void attn_combine(const u16* __restrict__ Opart, const float2* __restrict__ ml,
                  u16* __restrict__ attn) {
  int idx = blockIdx.x * 256 + threadIdx.x;       // T*HID/8 threads
  int e8 = idx * 8;
  int qrow = e8 >> 11;
  int col = e8 & (HID - 1);
  int h = col >> 7, coll = col & 127;
  int bq = qrow >> 7, ql = qrow & 127;
  int a = bq >> 2, r = bq & 3;
  int base = h * CPH + (a + 1) * (2 * a + r);
  int n = (bq + 4) >> 2;

  float m = -1e30f;
  for (int c = 0; c < n; ++c) m = fmaxf(m, ml[(size_t)(base + c) * 128 + ql].x);
  float lsum = 0.0f;
  float o[8] = {};
  for (int c = 0; c < n; ++c) {
    float2 mlc = ml[(size_t)(base + c) * 128 + ql];
    float wgt = exp2f(mlc.x - m);
    lsum += mlc.y * wgt;
    const u16* src = Opart + ((size_t)(base + c) * 128 + ql) * 128 + coll;
    ushort4 v0 = *(const ushort4*)src;
    ushort4 v1 = *(const ushort4*)(src + 4);
    o[0] += bf2f(v0.x) * wgt; o[1] += bf2f(v0.y) * wgt;
    o[2] += bf2f(v0.z) * wgt; o[3] += bf2f(v0.w) * wgt;
    o[4] += bf2f(v1.x) * wgt; o[5] += bf2f(v1.y) * wgt;
    o[6] += bf2f(v1.z) * wgt; o[7] += bf2f(v1.w) * wgt;
  }
  float rl = 1.0f / lsum;
  uint4 w;
  w.x = (u32)f2bf(o[0] * rl) | ((u32)f2bf(o[1] * rl) << 16);
  w.y = (u32)f2bf(o[2] * rl) | ((u32)f2bf(o[3] * rl) << 16);
  w.z = (u32)f2bf(o[4] * rl) | ((u32)f2bf(o[5] * rl) << 16);
  w.w = (u32)f2bf(o[6] * rl) | ((u32)f2bf(o[7] * rl) << 16);
  *(uint4*)&attn[e8] = w;
}

extern "C" void kernel_launch(void* const* d_in, const int* in_sizes, int n_in,
                              void* d_out, int out_size, void* d_ws, size_t ws_size,
                              hipStream_t stream) {
  const float* hidden    = (const float*)d_in[0];
  const int*   positions = (const int*)d_in[1];
  const float* w_qkv     = (const float*)d_in[2];
  const float* w_o       = (const float*)d_in[3];
  float* out = (float*)d_out;

  char* p = (char*)d_ws;
  u16* woT    = (u16*)p;  p += (size_t)HID * HID * 2;
  u16* Qh     = (u16*)p;  p += (size_t)T_SEQ * HID * 2;
  u16* Kh     = (u16*)p;  p += (size_t)T_SEQ * HID * 2;
  u16* Vt     = (u16*)p;  p += (size_t)T_SEQ * HID * 2;
  u16* attn_b = (u16*)p;  p += (size_t)T_SEQ * HID * 2;
  // union region: {hs_b, wqkvT, qkvb} (dead after vtrans) overlaps {Opart, ml}
  // (written by attn_fwd, strictly later in stream order).
  char* un = p;
  u16* hs_b   = (u16*)un;
  u16* wqkvT  = (u16*)(un + (size_t)T_SEQ * HID * 2);
  u16* qkvb   = (u16*)(un + (size_t)T_SEQ * HID * 2 + (size_t)QKVN * HID * 2);
  u16* Opart  = (u16*)un;
  float2* ml  = (float2*)(un + (size_t)NH * CPH * 128 * 128 * 2);

  cast_f32_bf16<<<(T_SEQ * HID / 4 + 255) / 256, 256, 0, stream>>>(hidden, hs_b, T_SEQ * HID);
  transpose_cast<<<dim3(QKVN / 64, HID / 64), 256, 0, stream>>>(w_qkv, wqkvT, HID, QKVN);
  transpose_cast<<<dim3(HID / 64, HID / 64), 256, 0, stream>>>(w_o, woT, HID, HID);
  gemm_bf16_bt<u16><<<dim3(QKVN / 128, T_SEQ / 128), 256, 0, stream>>>(hs_b, wqkvT, qkvb,
                                                                       T_SEQ, QKVN, HID);
  rope_reorg<<<(T_SEQ * NH * 64 + 255) / 256, 256, 0, stream>>>(qkvb, positions, Qh, Kh);
  vtrans<<<dim3(T_SEQ / 64, NH), 256, 0, stream>>>(qkvb, Vt);
  attn_fwd<<<NH * CPH, 256, 0, stream>>>(Qh, Kh, Vt, Opart, ml);
  attn_combine<<<T_SEQ * HID / 8 / 256, 256, 0, stream>>>(Opart, ml, attn_b);
  gemm_bf16_bt<float><<<dim3(HID / 128, T_SEQ / 128), 256, 0, stream>>>(attn_b, woT, out,
                                                                        T_SEQ, HID, HID);
}